// Round 11
// baseline (634.823 us; speedup 1.0000x reference)
//
#include <hip/hip_runtime.h>
#include <stdint.h>

#define B_  4096
#define H_  512
#define S_  16384
#define KT_ 16            // H_/32 K-steps of 32
#define NEED_MAIN 131072  // K*B
#define NEED_DEAD 65536   // DEAD_K*B
#define DEAD_THRESH 5

#define T_LO 1.05078125f         // exact bin edge: 0x3F868000
#define BIN_BASE 0x3F800000u
#define BIN_SHIFT 13
#define NBIN 2048                // covers [1.0, 4.0)
#define REG_W 8                  // f64-rescue region = [b*-8, b*+7]; uncond >= b*+8
#define PAD_BINS 2
#define NSUB 8192
#define TIECAP 512

#define NSEG 32768               // 4096 blocks x 8 waves
#define CAPSEG_M 128             // lambda ~21
#define CAPSEG_D 64              // lambda ~10
#define BNDCAP 16384
#define CAPROW_M 192
#define CAPROW_D 128

typedef __bf16 bf16x8 __attribute__((ext_vector_type(8)));
typedef float f32x4 __attribute__((ext_vector_type(4)));
typedef unsigned short ushort8 __attribute__((ext_vector_type(8)));

__device__ __forceinline__ uint32_t binOf(float v) {
    uint32_t b = (__float_as_uint(v) - BIN_BASE) >> BIN_SHIFT;
    return b > (NBIN - 1) ? (NBIN - 1) : b;
}
__device__ __forceinline__ uint16_t f2bf(float f) {
    uint32_t u = __float_as_uint(f);
    uint32_t r = u + 0x7FFFu + ((u >> 16) & 1u);   // RNE
    return (uint16_t)(r >> 16);
}
__device__ __forceinline__ float bf2f(uint16_t b) {
    return __uint_as_float((uint32_t)b << 16);
}
__device__ __forceinline__ void gload16(const void* g, void* l) {
    __builtin_amdgcn_global_load_lds((const __attribute__((address_space(1))) uint32_t*)g,
                                     (__attribute__((address_space(3))) uint32_t*)l, 16, 0, 0);
}

// ---------------- W2 [H,S] -> W2T [S,H] as bf16 ----------------
__global__ __launch_bounds__(256) void transpose_k(const float* __restrict__ W2,
                                                   uint16_t* __restrict__ W2T) {
    __shared__ float tile[32][33];
    int s0 = blockIdx.x * 32, h0 = blockIdx.y * 32;
    int tx = threadIdx.x & 31, ty = threadIdx.x >> 5;
#pragma unroll
    for (int i = 0; i < 4; i++) {
        int h = h0 + ty + i * 8;
        tile[ty + i * 8][tx] = W2[(size_t)h * S_ + s0 + tx];
    }
    __syncthreads();
#pragma unroll
    for (int i = 0; i < 4; i++) {
        int s = s0 + ty + i * 8;
        W2T[(size_t)s * H_ + h0 + tx] = f2bf(tile[tx][ty + i * 8]);
    }
}

// ------- split x-b2 -> AhT,AlT (blocks 0..1023) and w1 -> WhT (blocks 1024..5119) ----
__global__ __launch_bounds__(256) void split_all_k(const float* __restrict__ x,
                                                   const float* __restrict__ w1,
                                                   const float* __restrict__ b2,
                                                   uint8_t* __restrict__ AhT,
                                                   uint8_t* __restrict__ AlT,
                                                   uint8_t* __restrict__ WhT) {
    int isX = blockIdx.x < 1024;
    int tid = (isX ? blockIdx.x : blockIdx.x - 1024) * 256 + threadIdx.x;
    int r = tid >> 6, h8 = tid & 63;
    int k0 = h8 << 3;
    const float* src = isX ? x : w1;
    const float* s = src + (size_t)r * H_ + k0;
    float4 v0 = *(const float4*)s, v1 = *(const float4*)(s + 4);
    float a[8] = {v0.x, v0.y, v0.z, v0.w, v1.x, v1.y, v1.z, v1.w};
    if (isX) {
        float4 c0 = *(const float4*)(b2 + k0), c1 = *(const float4*)(b2 + k0 + 4);
        a[0] -= c0.x; a[1] -= c0.y; a[2] -= c0.z; a[3] -= c0.w;
        a[4] -= c1.x; a[5] -= c1.y; a[6] -= c1.z; a[7] -= c1.w;
    }
    ushort8 Hh, Ll;
#pragma unroll
    for (int e = 0; e < 8; e++) {
        uint16_t h = f2bf(a[e]);
        Hh[e] = h;
        Ll[e] = f2bf(a[e] - bf2f(h));
    }
    int rb = r >> 7, kt = k0 >> 5;
    int mf = (r >> 4) & 7;
    int ln = (r & 15) | (((k0 >> 3) & 3) << 4);
    size_t byte = ((size_t)rb * KT_ + kt) * 8192 + (size_t)mf * 1024 + (size_t)ln * 16;
    if (isX) {
        *(ushort8*)(AhT + byte) = Hh;
        *(ushort8*)(AlT + byte) = Ll;
    } else {
        *(ushort8*)(WhT + byte) = Hh;
    }
}

// ------- f = relu((x-b2)@W1^T + b1) via 2x bf16 MFMA, 8 waves of 64x32, collect ------
__global__ __launch_bounds__(512) void gemm_fused(const uint8_t* __restrict__ AhT,
                                                  const uint8_t* __restrict__ AlT,
                                                  const uint8_t* __restrict__ WhT,
                                                  const float* __restrict__ b1,
                                                  const int* __restrict__ deadf,
                                                  uint2* __restrict__ glM,
                                                  uint2* __restrict__ glD,
                                                  uint32_t* __restrict__ bcM,
                                                  uint32_t* __restrict__ bcD,
                                                  float* __restrict__ fsp) {
    __shared__ uint8_t lds[2][3][8192];   // [buf][Ah,Al,Wh][tile]
    const int tid = threadIdx.x;
    const int lane = tid & 63, w = tid >> 6;     // 8 waves
    const int wr = w >> 2, wc = w & 3;           // wave tile 64x32: wr 0..1, wc 0..3
    const int lin = blockIdx.y * 512 + blockIdx.x;
    const int xcd = lin & 7, idx = lin >> 3;
    const int mb = xcd * 4 + (idx & 3), nb = idx >> 2;   // mb-fastest within XCD

    const uint8_t* gAh = AhT + (size_t)mb * KT_ * 8192;
    const uint8_t* gAl = AlT + (size_t)mb * KT_ * 8192;
    const uint8_t* gBh = WhT + (size_t)nb * KT_ * 8192;

    f32x4 acc[4][2];
#pragma unroll
    for (int i = 0; i < 4; i++)
#pragma unroll
        for (int j = 0; j < 2; j++) acc[i][j] = (f32x4){0.f, 0.f, 0.f, 0.f};

    auto stage = [&](int buf, int kt) {
        size_t tb = (size_t)kt * 8192;
        int o = tid * 16;
        gload16(gAh + tb + o, &lds[buf][0][o]);
        gload16(gAl + tb + o, &lds[buf][1][o]);
        gload16(gBh + tb + o, &lds[buf][2][o]);
    };

    // fsp zero-fill: block owns F tile [mb*128, +128) x [nb*128, +128)
    float* Fb = fsp + (size_t)(mb * 128) * S_ + nb * 128;
    const int zc4 = (tid & 31) * 4, zr0 = tid >> 5;   // 16 rows x 128 cols per pass
    const float4 zf4 = {0.f, 0.f, 0.f, 0.f};

    stage(0, 0);
    __syncthreads();
    for (int kt = 0; kt < KT_; kt++) {
        int cur = kt & 1;
        if (kt + 1 < KT_) stage(cur ^ 1, kt + 1);
        if (kt < 8) *(float4*)(Fb + (size_t)(zr0 + kt * 16) * S_ + zc4) = zf4;
        bf16x8 ah[4], al[4], bh[2];
#pragma unroll
        for (int i = 0; i < 4; i++) {
            int offA = (wr * 4 + i) * 1024 + lane * 16;
            ah[i] = *(const bf16x8*)&lds[cur][0][offA];
            al[i] = *(const bf16x8*)&lds[cur][1][offA];
        }
#pragma unroll
        for (int j = 0; j < 2; j++) {
            int offB = (wc * 2 + j) * 1024 + lane * 16;
            bh[j] = *(const bf16x8*)&lds[cur][2][offB];
        }
#pragma unroll
        for (int i = 0; i < 4; i++)
#pragma unroll
            for (int j = 0; j < 2; j++)
                acc[i][j] = __builtin_amdgcn_mfma_f32_16x16x32_bf16(ah[i], bh[j], acc[i][j], 0, 0, 0);
#pragma unroll
        for (int i = 0; i < 4; i++)
#pragma unroll
            for (int j = 0; j < 2; j++)
                acc[i][j] = __builtin_amdgcn_mfma_f32_16x16x32_bf16(al[i], bh[j], acc[i][j], 0, 0, 0);
        __syncthreads();
    }

    const int col0 = nb * 128 + wc * 32 + (lane & 15);
    const int row0 = mb * 128 + wr * 64 + (lane >> 4) * 4;
    float b1v[2];
    int dd[2];
#pragma unroll
    for (int j = 0; j < 2; j++) {
        b1v[j] = b1[col0 + j * 16];
        dd[j] = (deadf[col0 + j * 16] >= DEAD_THRESH) ? 1 : 0;
    }
    const uint32_t gseg = (uint32_t)(mb * 128 + nb) * 8 + w;
    uint2* segM = glM + (size_t)gseg * CAPSEG_M;
    uint2* segD = glD + (size_t)gseg * CAPSEG_D;
    const uint64_t lmlt = ((uint64_t)1 << lane) - 1;
    uint32_t runM = 0, runD = 0;
#pragma unroll
    for (int i = 0; i < 4; i++)
#pragma unroll
        for (int j = 0; j < 2; j++)
#pragma unroll
            for (int r = 0; r < 4; r++) {
                float v = fmaxf(acc[i][j][r] + b1v[j], 0.0f);
                bool pass = v >= T_LO;
                uint64_t mask = __ballot(pass);
                if (mask) {
                    uint32_t prefix = (uint32_t)__popcll(mask & lmlt);
                    uint2 ent;
                    ent.x = (uint32_t)(row0 + i * 16 + r) * S_ + (uint32_t)(col0 + j * 16);
                    ent.y = __float_as_uint(v);
                    if (pass && runM + prefix < CAPSEG_M) segM[runM + prefix] = ent;
                    runM += (uint32_t)__popcll(mask);
                    bool dp = pass && dd[j];
                    uint64_t dmask = __ballot(dp);
                    if (dmask) {
                        uint32_t dprefix = (uint32_t)__popcll(dmask & lmlt);
                        if (dp && runD + dprefix < CAPSEG_D) segD[runD + dprefix] = ent;
                        runD += (uint32_t)__popcll(dmask);
                    }
                }
            }
    if (lane == 0) {
        bcM[gseg] = runM < CAPSEG_M ? runM : CAPSEG_M;
        bcD[gseg] = runD < CAPSEG_D ? runD : CAPSEG_D;
    }
}

// ---------------- exclusive prefix over segment counts -> offsets + totals --------
__global__ __launch_bounds__(256) void seg_scan_k(const uint32_t* __restrict__ bcM,
                                                  const uint32_t* __restrict__ bcD,
                                                  uint32_t* __restrict__ soM,
                                                  uint32_t* __restrict__ soD,
                                                  uint32_t* __restrict__ cnts) {
    __shared__ uint32_t part[256];
    const int t = threadIdx.x;
    for (int sel = 0; sel < 2; sel++) {
        const uint32_t* bc = sel ? bcD : bcM;
        uint32_t* so = sel ? soD : soM;
        uint32_t s = 0;
        for (int i = 0; i < NSEG / 256; i++) s += bc[t * (NSEG / 256) + i];
        part[t] = s;
        __syncthreads();
        for (int d = 1; d < 256; d <<= 1) {
            uint32_t v = (t >= d) ? part[t - d] : 0;
            __syncthreads();
            part[t] += v;
            __syncthreads();
        }
        uint32_t run = (t == 0) ? 0 : part[t - 1];
        for (int i = 0; i < NSEG / 256; i++) {
            uint32_t c = bc[t * (NSEG / 256) + i];
            so[t * (NSEG / 256) + i] = run;
            run += c;
        }
        if (t == 255) cnts[sel] = run;
        __syncthreads();
    }
}

// ---------------- compact segments to dense lists + histogram, y=0 M / y=1 D ------
__global__ __launch_bounds__(256) void compact_hist_k(const uint2* __restrict__ glM,
                                                      const uint2* __restrict__ glD,
                                                      const uint32_t* __restrict__ bcM,
                                                      const uint32_t* __restrict__ bcD,
                                                      const uint32_t* __restrict__ soM,
                                                      const uint32_t* __restrict__ soD,
                                                      uint2* __restrict__ cmpM,
                                                      uint2* __restrict__ cmpD,
                                                      uint32_t* __restrict__ ghM,
                                                      uint32_t* __restrict__ ghD) {
    __shared__ uint32_t h[NBIN];
    int sel = blockIdx.y;
    const uint2* list = sel ? glD : glM;
    const uint32_t* bc = sel ? bcD : bcM;
    const uint32_t* so = sel ? soD : soM;
    uint2* cmp = sel ? cmpD : cmpM;
    uint32_t cap = sel ? CAPSEG_D : CAPSEG_M;
    uint32_t* gh = sel ? ghD : ghM;
    for (int i = threadIdx.x; i < NBIN; i += 256) h[i] = 0;
    __syncthreads();
    const int wv = threadIdx.x >> 6, lane = threadIdx.x & 63;
    for (uint32_t seg = blockIdx.x * 4 + wv; seg < NSEG; seg += gridDim.x * 4) {
        uint32_t n = bc[seg], off = so[seg];
        for (uint32_t i = lane; i < n; i += 64) {
            uint2 e = list[(size_t)seg * cap + i];
            cmp[off + i] = e;
            atomicAdd(&h[binOf(__uint_as_float(e.y))], 1u);
        }
    }
    __syncthreads();
    for (int i = threadIdx.x; i < NBIN; i += 256)
        if (h[i]) atomicAdd(&gh[i], h[i]);
}

// ---------------- find boundary bin b* (parallel chunked scan) ----------------
__global__ __launch_bounds__(256) void scan_k(const uint32_t* __restrict__ ghM,
                                              const uint32_t* __restrict__ ghD,
                                              uint32_t* __restrict__ scal) {
    __shared__ uint32_t h[NBIN];
    __shared__ uint32_t csum[64];
    for (int sel = 0; sel < 2; sel++) {
        const uint32_t* gh = sel ? ghD : ghM;
        uint32_t need = sel ? NEED_DEAD : NEED_MAIN;
        for (int i = threadIdx.x; i < NBIN; i += 256) h[i] = gh[i];
        __syncthreads();
        if (threadIdx.x < 64) {
            uint32_t s = 0;
#pragma unroll
            for (int j = 0; j < 32; j++) s += h[threadIdx.x * 32 + j];
            csum[threadIdx.x] = s;
        }
        __syncthreads();
        if (threadIdx.x == 0) {
            uint32_t cum = 0; int c = 63;
            for (; c > 0; c--) { uint32_t cc = csum[c]; if (cum + cc >= need) break; cum += cc; }
            int b = c * 32 + 31;
            for (; b > c * 32; b--) { uint32_t cc = h[b]; if (cum + cc >= need) break; cum += cc; }
            uint32_t extra = 0;
            for (int j = b + 1; j < b + REG_W && j < NBIN; j++) extra += h[j];
            scal[sel ? 2 : 0] = (uint32_t)b;
            scal[sel ? 3 : 1] = need - cum + extra;
        }
        __syncthreads();
    }
}

// ------ fused: pull boundary-region entries AND f64-recompute (wave-cooperative) ------
__global__ __launch_bounds__(256) void bnd_fused_k(const uint2* __restrict__ cmpM,
                                                   const uint2* __restrict__ cmpD,
                                                   const uint32_t* __restrict__ scal,
                                                   const float* __restrict__ x,
                                                   const float* __restrict__ w1,
                                                   const float* __restrict__ b1,
                                                   const float* __restrict__ b2,
                                                   uint2* __restrict__ bndM,
                                                   uint2* __restrict__ bndD,
                                                   double* __restrict__ bvM,
                                                   double* __restrict__ bvD,
                                                   uint32_t* __restrict__ cnts) {
    int sel = blockIdx.y;
    const uint2* list = sel ? cmpD : cmpM;
    uint2* bnd = sel ? bndD : bndM;
    double* bv64 = sel ? bvD : bvM;
    uint32_t n = cnts[sel];
    uint32_t bs = scal[sel ? 2 : 0];
    const int lane = threadIdx.x & 63, wv = threadIdx.x >> 6;
    const uint32_t stride = gridDim.x * 4 * 64;
    for (uint32_t base = (blockIdx.x * 4 + wv) * 64; base < n; base += stride) {
        uint32_t i = base + lane;
        uint2 ent = make_uint2(0u, 0u);
        bool pass = false;
        if (i < n) {
            ent = list[i];
            uint32_t bb = binOf(__uint_as_float(ent.y));
            pass = (bb + REG_W >= bs) && (bb <= bs + REG_W - 1);
        }
        uint64_t mm = __ballot(pass);
        while (mm) {
            int b = __ffsll((unsigned long long)mm) - 1;
            mm &= mm - 1;
            uint32_t ex_ = __shfl(ent.x, b, 64);
            uint32_t ey_ = __shfl(ent.y, b, 64);
            uint32_t pos = 0;
            if (lane == 0) pos = atomicAdd(&cnts[2 + sel], 1u);
            pos = __shfl(pos, 0, 64);
            if (pos >= BNDCAP) continue;
            uint32_t m = ex_ >> 14, s = ex_ & (S_ - 1);
            const float* xr = x + (size_t)m * H_;
            const float* wr = w1 + (size_t)s * H_;
            double sum = 0.0;
#pragma unroll
            for (int e = 0; e < 8; e++) {
                int k = lane + e * 64;
                sum += ((double)xr[k] - (double)b2[k]) * (double)wr[k];
            }
#pragma unroll
            for (int off = 32; off; off >>= 1) sum += __shfl_down(sum, off, 64);
            if (lane == 0) {
                double tot = sum + (double)b1[s];
                bv64[pos] = tot > 0.0 ? tot : 0.0;
                bnd[pos] = make_uint2(ex_, ey_);
            }
        }
    }
}

// ------ exact top-r' in region: O(n) histogram-select + tie rank; DIRECT writes ------
__global__ __launch_bounds__(1024) void rank_hist_k(const uint2* __restrict__ bndM,
                                                    const double* __restrict__ bvM,
                                                    const uint2* __restrict__ bndD,
                                                    const double* __restrict__ bvD,
                                                    uint32_t* __restrict__ cnts,
                                                    const uint32_t* __restrict__ scal,
                                                    float* __restrict__ fsp,
                                                    uint2* __restrict__ entM,
                                                    uint2* __restrict__ entD,
                                                    uint32_t* __restrict__ rcM,
                                                    uint32_t* __restrict__ rcD) {
    int sel = blockIdx.x;
    const uint2* bnd = sel ? bndD : bndM;
    const double* bv = sel ? bvD : bvM;
    uint2* entries = sel ? entD : entM;
    uint32_t* rowCnt = sel ? rcD : rcM;
    const int capRow = sel ? CAPROW_D : CAPROW_M;
    uint32_t n = cnts[2 + sel]; if (n > BNDCAP) n = BNDCAP;
    uint32_t r = scal[sel ? 3 : 1]; if (r > n) r = n;
    uint32_t bs = scal[sel ? 2 : 0];
    uint32_t loBin = bs - (REG_W + PAD_BINS);
    uint32_t hiBin = bs + (REG_W + PAD_BINS);
    double lo = (double)__uint_as_float(BIN_BASE + (loBin << BIN_SHIFT));
    double hi = (double)__uint_as_float(BIN_BASE + (hiBin << BIN_SHIFT));
    double scale = (double)NSUB / (hi - lo);

    __shared__ uint32_t h[NSUB];
    __shared__ uint32_t cs[1024];
    __shared__ uint32_t c2[64];
    __shared__ uint32_t sCb, sAbove, sTieCnt;
    __shared__ double tieV[TIECAP];
    __shared__ uint2 tieE[TIECAP];
    const int t = threadIdx.x;
    for (int i = t; i < NSUB; i += 1024) h[i] = 0;
    if (t == 0) sTieCnt = 0;
    __syncthreads();
    for (uint32_t i = t; i < n; i += 1024) {
        double v = bv[i];
        int k = (int)((v - lo) * scale);
        k = k < 0 ? 0 : (k > NSUB - 1 ? NSUB - 1 : k);
        atomicAdd(&h[k], 1u);
    }
    __syncthreads();
    {
        uint32_t s = 0;
#pragma unroll
        for (int j = 0; j < 8; j++) s += h[t * 8 + j];
        cs[t] = s;
    }
    __syncthreads();
    if (t < 64) {
        uint32_t s = 0;
#pragma unroll
        for (int j = 0; j < 16; j++) s += cs[t * 16 + j];
        c2[t] = s;
    }
    __syncthreads();
    if (t == 0) {
        uint32_t cum = 0; int w2 = 63;
        for (; w2 > 0; w2--) { if (cum + c2[w2] >= r) break; cum += c2[w2]; }
        int c = w2 * 16 + 15;
        for (; c > w2 * 16; c--) { if (cum + cs[c] >= r) break; cum += cs[c]; }
        int b = c * 8 + 7;
        for (; b > c * 8; b--) { if (cum + h[b] >= r) break; cum += h[b]; }
        sCb = (uint32_t)b;
        sAbove = cum;
    }
    __syncthreads();
    const uint32_t cb = sCb;
    uint32_t rr = r - sAbove;
    const int lane = t & 63;
    const uint64_t lmlt = ((uint64_t)1 << lane) - 1;
    for (uint32_t i0 = 0; i0 < n; i0 += 1024) {
        uint32_t i = i0 + t;
        bool valid = i < n;
        double v = valid ? bv[i] : -1.0;
        uint32_t k = 0;
        if (valid) {
            int kk = (int)((v - lo) * scale);
            k = (uint32_t)(kk < 0 ? 0 : (kk > NSUB - 1 ? NSUB - 1 : kk));
        }
        if (valid && k > cb) {
            uint2 ent = bnd[i];
            float fv = __uint_as_float(ent.y);
            if (!sel) fsp[ent.x] = fv;
            uint32_t row = ent.x >> 14;
            uint32_t slot = atomicAdd(&rowCnt[row], 1u);
            if (slot < (uint32_t)capRow)
                entries[(size_t)row * capRow + slot] = make_uint2(ent.x & (S_ - 1), ent.y);
        }
        bool tie = valid && k == cb;
        uint64_t tm = __ballot(tie);
        if (tm) {
            uint32_t base = 0;
            if (lane == 0) base = atomicAdd(&sTieCnt, (uint32_t)__popcll(tm));
            base = __shfl(base, 0, 64);
            if (tie) {
                uint32_t p = base + __popcll(tm & lmlt);
                if (p < TIECAP) { tieV[p] = v; tieE[p] = bnd[i]; }
            }
        }
    }
    __syncthreads();
    uint32_t tc = sTieCnt; if (tc > TIECAP) tc = TIECAP;
    if (rr > tc) rr = tc;
    if (t < (int)tc) {
        double vi = tieV[t]; uint32_t ii = tieE[t].x;
        uint32_t rank = 0;
        for (uint32_t j = 0; j < tc; j++) {
            double vj = tieV[j]; uint32_t ij = tieE[j].x;
            rank += (vj > vi || (vj == vi && ij < ii)) ? 1u : 0u;
        }
        if (rank < rr) {
            uint2 ent = tieE[t];
            float fv = __uint_as_float(ent.y);
            if (!sel) fsp[ent.x] = fv;
            uint32_t row = ent.x >> 14;
            uint32_t slot = atomicAdd(&rowCnt[row], 1u);
            if (slot < (uint32_t)capRow)
                entries[(size_t)row * capRow + slot] = make_uint2(ent.x & (S_ - 1), ent.y);
        }
    }
}

// ---------------- scatter uncond picks (bins >= b*+REG_W) from dense lists ----------
__global__ __launch_bounds__(256) void scatter_list_k(const uint2* __restrict__ cmpM,
                                                      const uint2* __restrict__ cmpD,
                                                      const uint32_t* __restrict__ cnts,
                                                      const uint32_t* __restrict__ scal,
                                                      float* __restrict__ fsp,
                                                      uint2* __restrict__ entM,
                                                      uint2* __restrict__ entD,
                                                      uint32_t* __restrict__ rcM,
                                                      uint32_t* __restrict__ rcD) {
    int sel = blockIdx.y;
    const uint2* list = sel ? cmpD : cmpM;
    uint2* entries = sel ? entD : entM;
    uint32_t* rowCnt = sel ? rcD : rcM;
    int capRow = sel ? CAPROW_D : CAPROW_M;
    uint32_t n = cnts[sel];
    uint32_t bsReg = scal[sel ? 2 : 0] + REG_W - 1;
    for (uint32_t i = blockIdx.x * 256 + threadIdx.x; i < n; i += gridDim.x * 256) {
        uint2 ent = list[i];
        float v = __uint_as_float(ent.y);
        if (binOf(v) <= bsReg) continue;   // region handled by rank_hist_k
        if (!sel) fsp[ent.x] = v;
        uint32_t row = ent.x >> 14;
        uint32_t slot = atomicAdd(&rowCnt[row], 1u);
        if (slot < (uint32_t)capRow)
            entries[(size_t)row * capRow + slot] = make_uint2(ent.x & (S_ - 1), ent.y);
    }
}

// ---------------- sparse decode: x_rec & dead_x (bf16 W2T) ----------------
__global__ __launch_bounds__(512) void decode_k(const uint2* __restrict__ entM,
                                                const uint32_t* __restrict__ rcM,
                                                const uint2* __restrict__ entD,
                                                const uint32_t* __restrict__ rcD,
                                                const uint16_t* __restrict__ W2T,
                                                const float* __restrict__ b2,
                                                float* __restrict__ xrec,
                                                float* __restrict__ deadx) {
    __shared__ uint2 em[CAPROW_M];
    __shared__ uint2 ed[CAPROW_D];
    int b = blockIdx.x, h = threadIdx.x;
    uint32_t nm = rcM[b]; if (nm > CAPROW_M) nm = CAPROW_M;
    uint32_t nd = rcD[b]; if (nd > CAPROW_D) nd = CAPROW_D;
    for (uint32_t i = h; i < nm; i += 512) em[i] = entM[(size_t)b * CAPROW_M + i];
    for (uint32_t i = h; i < nd; i += 512) ed[i] = entD[(size_t)b * CAPROW_D + i];
    __syncthreads();
    float bias = b2[h];
    float a = bias, d = bias;
    for (uint32_t i = 0; i < nm; i++)
        a = fmaf(__uint_as_float(em[i].y), bf2f(W2T[(size_t)em[i].x * H_ + h]), a);
    for (uint32_t i = 0; i < nd; i++)
        d = fmaf(__uint_as_float(ed[i].y), bf2f(W2T[(size_t)ed[i].x * H_ + h]), d);
    xrec[(size_t)b * H_ + h] = a;
    deadx[(size_t)b * H_ + h] = d;
}

extern "C" void kernel_launch(void* const* d_in, const int* in_sizes, int n_in,
                              void* d_out, int out_size, void* d_ws, size_t ws_size,
                              hipStream_t stream) {
    const float* x = (const float*)d_in[0];
    const float* w1 = (const float*)d_in[1];
    const float* b1 = (const float*)d_in[2];
    const float* w2 = (const float*)d_in[3];
    const float* b2 = (const float*)d_in[4];
    const int* deadf = (const int*)d_in[5];

    float* out = (float*)d_out;
    float* xrec = out;
    float* fsp = out + (size_t)B_ * H_;
    float* deadx = out + (size_t)B_ * H_ + (size_t)B_ * S_;

    uint8_t* w = (uint8_t*)d_ws;
    size_t off = 0;
    auto alloc = [&](size_t bytes) { uint8_t* p = w + off; off = (off + bytes + 255) & ~(size_t)255; return p; };

    uint16_t* W2T = (uint16_t*)alloc((size_t)S_ * H_ * 2);
    uint8_t* ctrl = alloc(NBIN * 8 + 128 + (size_t)B_ * 8);
    uint32_t* ghM = (uint32_t*)ctrl;
    uint32_t* ghD = (uint32_t*)(ctrl + NBIN * 4);
    uint32_t* cnts = (uint32_t*)(ctrl + NBIN * 8);         // [0]totM [1]totD [2]bndM [3]bndD
    uint32_t* scal = (uint32_t*)(ctrl + NBIN * 8 + 64);    // [0]bstarM [1]rM [2]bstarD [3]rD
    uint32_t* rcM = (uint32_t*)(ctrl + NBIN * 8 + 128);
    uint32_t* rcD = (uint32_t*)(ctrl + NBIN * 8 + 128 + B_ * 4);
    size_t ctrlBytes = NBIN * 8 + 128 + (size_t)B_ * 8;

    uint2* listM = (uint2*)alloc((size_t)NSEG * CAPSEG_M * 8);
    uint2* listD = (uint2*)alloc((size_t)NSEG * CAPSEG_D * 8);
    uint32_t* bcM = (uint32_t*)alloc((size_t)NSEG * 4);
    uint32_t* bcD = (uint32_t*)alloc((size_t)NSEG * 4);
    uint32_t* soM = (uint32_t*)alloc((size_t)NSEG * 4);
    uint32_t* soD = (uint32_t*)alloc((size_t)NSEG * 4);
    uint2* cmpM = (uint2*)alloc((size_t)NSEG * CAPSEG_M * 8);
    uint2* cmpD = (uint2*)alloc((size_t)NSEG * CAPSEG_D * 8);
    uint2* bndM = (uint2*)alloc((size_t)BNDCAP * 8);
    uint2* bndD = (uint2*)alloc((size_t)BNDCAP * 8);
    double* bvM = (double*)alloc((size_t)BNDCAP * 8);
    double* bvD = (double*)alloc((size_t)BNDCAP * 8);
    uint2* entM = (uint2*)alloc((size_t)B_ * CAPROW_M * 8);
    uint2* entD = (uint2*)alloc((size_t)B_ * CAPROW_D * 8);
    uint8_t* AhT = alloc((size_t)B_ * H_ * 2);
    uint8_t* AlT = alloc((size_t)B_ * H_ * 2);
    uint8_t* WhT = alloc((size_t)S_ * H_ * 2);

    (void)hipMemsetAsync(ctrl, 0, ctrlBytes, stream);
    transpose_k<<<dim3(S_ / 32, H_ / 32), 256, 0, stream>>>(w2, W2T);
    split_all_k<<<5120, 256, 0, stream>>>(x, w1, b2, AhT, AlT, WhT);
    gemm_fused<<<dim3(512, 8), 512, 0, stream>>>(AhT, AlT, WhT, b1, deadf,
                                                 listM, listD, bcM, bcD, fsp);
    seg_scan_k<<<1, 256, 0, stream>>>(bcM, bcD, soM, soD, cnts);
    compact_hist_k<<<dim3(256, 2), 256, 0, stream>>>(listM, listD, bcM, bcD, soM, soD,
                                                     cmpM, cmpD, ghM, ghD);
    scan_k<<<1, 256, 0, stream>>>(ghM, ghD, scal);
    bnd_fused_k<<<dim3(1024, 2), 256, 0, stream>>>(cmpM, cmpD, scal, x, w1, b1, b2,
                                                   bndM, bndD, bvM, bvD, cnts);
    rank_hist_k<<<2, 1024, 0, stream>>>(bndM, bvM, bndD, bvD, cnts, scal,
                                        fsp, entM, entD, rcM, rcD);
    scatter_list_k<<<dim3(1024, 2), 256, 0, stream>>>(cmpM, cmpD, cnts, scal, fsp,
                                                      entM, entD, rcM, rcD);
    decode_k<<<B_, 512, 0, stream>>>(entM, rcM, entD, rcD, W2T, b2, xrec, deadx);
}

// Round 12
// 507.940 us; speedup vs baseline: 1.2498x; 1.2498x over previous
//
#include <hip/hip_runtime.h>
#include <stdint.h>

#define B_  4096
#define H_  512
#define S_  16384
#define KT_ 16            // H_/32 K-steps of 32
#define NEED_MAIN 131072  // K*B
#define NEED_DEAD 65536   // DEAD_K*B
#define DEAD_THRESH 5

#define T_LO 1.05078125f         // exact bin edge: 0x3F868000
#define BIN_BASE 0x3F800000u
#define BIN_SHIFT 13
#define NBIN 2048                // covers [1.0, 4.0)
#define REG_W 8                  // f64-rescue region = [b*-8, b*+7]; uncond >= b*+8
#define PAD_BINS 2
#define NSUB 8192
#define TIECAP 512

#define NSEG 32768               // 4096 blocks x 8 waves
#define CAPSEG_M 128             // lambda ~21
#define CAPSEG_D 64              // lambda ~10
#define BNDCAP 16384
#define CAPROW_M 192
#define CAPROW_D 128

typedef __bf16 bf16x8 __attribute__((ext_vector_type(8)));
typedef float f32x4 __attribute__((ext_vector_type(4)));
typedef unsigned short ushort8 __attribute__((ext_vector_type(8)));

__device__ __forceinline__ uint32_t binOf(float v) {
    uint32_t b = (__float_as_uint(v) - BIN_BASE) >> BIN_SHIFT;
    return b > (NBIN - 1) ? (NBIN - 1) : b;
}
__device__ __forceinline__ uint16_t f2bf(float f) {
    uint32_t u = __float_as_uint(f);
    uint32_t r = u + 0x7FFFu + ((u >> 16) & 1u);   // RNE
    return (uint16_t)(r >> 16);
}
__device__ __forceinline__ float bf2f(uint16_t b) {
    return __uint_as_float((uint32_t)b << 16);
}
__device__ __forceinline__ void gload16(const void* g, void* l) {
    __builtin_amdgcn_global_load_lds((const __attribute__((address_space(1))) uint32_t*)g,
                                     (__attribute__((address_space(3))) uint32_t*)l, 16, 0, 0);
}

// ---------------- W2 [H,S] -> W2T [S,H] as bf16 ----------------
__global__ __launch_bounds__(256) void transpose_k(const float* __restrict__ W2,
                                                   uint16_t* __restrict__ W2T) {
    __shared__ float tile[32][33];
    int s0 = blockIdx.x * 32, h0 = blockIdx.y * 32;
    int tx = threadIdx.x & 31, ty = threadIdx.x >> 5;
#pragma unroll
    for (int i = 0; i < 4; i++) {
        int h = h0 + ty + i * 8;
        tile[ty + i * 8][tx] = W2[(size_t)h * S_ + s0 + tx];
    }
    __syncthreads();
#pragma unroll
    for (int i = 0; i < 4; i++) {
        int s = s0 + ty + i * 8;
        W2T[(size_t)s * H_ + h0 + tx] = f2bf(tile[tx][ty + i * 8]);
    }
}

// ------- split x-b2 -> AhT,AlT (blocks 0..1023) and w1 -> WhT (blocks 1024..5119) ----
__global__ __launch_bounds__(256) void split_all_k(const float* __restrict__ x,
                                                   const float* __restrict__ w1,
                                                   const float* __restrict__ b2,
                                                   uint8_t* __restrict__ AhT,
                                                   uint8_t* __restrict__ AlT,
                                                   uint8_t* __restrict__ WhT) {
    int isX = blockIdx.x < 1024;
    int tid = (isX ? blockIdx.x : blockIdx.x - 1024) * 256 + threadIdx.x;
    int r = tid >> 6, h8 = tid & 63;
    int k0 = h8 << 3;
    const float* src = isX ? x : w1;
    const float* s = src + (size_t)r * H_ + k0;
    float4 v0 = *(const float4*)s, v1 = *(const float4*)(s + 4);
    float a[8] = {v0.x, v0.y, v0.z, v0.w, v1.x, v1.y, v1.z, v1.w};
    if (isX) {
        float4 c0 = *(const float4*)(b2 + k0), c1 = *(const float4*)(b2 + k0 + 4);
        a[0] -= c0.x; a[1] -= c0.y; a[2] -= c0.z; a[3] -= c0.w;
        a[4] -= c1.x; a[5] -= c1.y; a[6] -= c1.z; a[7] -= c1.w;
    }
    ushort8 Hh, Ll;
#pragma unroll
    for (int e = 0; e < 8; e++) {
        uint16_t h = f2bf(a[e]);
        Hh[e] = h;
        Ll[e] = f2bf(a[e] - bf2f(h));
    }
    int rb = r >> 7, kt = k0 >> 5;
    int mf = (r >> 4) & 7;
    int ln = (r & 15) | (((k0 >> 3) & 3) << 4);
    size_t byte = ((size_t)rb * KT_ + kt) * 8192 + (size_t)mf * 1024 + (size_t)ln * 16;
    if (isX) {
        *(ushort8*)(AhT + byte) = Hh;
        *(ushort8*)(AlT + byte) = Ll;
    } else {
        *(ushort8*)(WhT + byte) = Hh;
    }
}

// ------- f = relu((x-b2)@W1^T + b1) via 2x bf16 MFMA, 8 waves of 64x32, collect ------
__global__ __launch_bounds__(512) void gemm_fused(const uint8_t* __restrict__ AhT,
                                                  const uint8_t* __restrict__ AlT,
                                                  const uint8_t* __restrict__ WhT,
                                                  const float* __restrict__ b1,
                                                  const int* __restrict__ deadf,
                                                  uint2* __restrict__ glM,
                                                  uint2* __restrict__ glD,
                                                  uint32_t* __restrict__ bcM,
                                                  uint32_t* __restrict__ bcD,
                                                  float* __restrict__ fsp) {
    __shared__ uint8_t lds[2][3][8192];   // [buf][Ah,Al,Wh][tile]
    const int tid = threadIdx.x;
    const int lane = tid & 63, w = tid >> 6;     // 8 waves
    const int wr = w >> 2, wc = w & 3;           // wave tile 64x32
    const int lin = blockIdx.y * 512 + blockIdx.x;
    const int xcd = lin & 7, idx = lin >> 3;
    const int mb = xcd * 4 + (idx & 3), nb = idx >> 2;   // mb-fastest within XCD

    const uint8_t* gAh = AhT + (size_t)mb * KT_ * 8192;
    const uint8_t* gAl = AlT + (size_t)mb * KT_ * 8192;
    const uint8_t* gBh = WhT + (size_t)nb * KT_ * 8192;

    f32x4 acc[4][2];
#pragma unroll
    for (int i = 0; i < 4; i++)
#pragma unroll
        for (int j = 0; j < 2; j++) acc[i][j] = (f32x4){0.f, 0.f, 0.f, 0.f};

    auto stage = [&](int buf, int kt) {
        size_t tb = (size_t)kt * 8192;
        int o = tid * 16;
        gload16(gAh + tb + o, &lds[buf][0][o]);
        gload16(gAl + tb + o, &lds[buf][1][o]);
        gload16(gBh + tb + o, &lds[buf][2][o]);
    };

    float* Fb = fsp + (size_t)(mb * 128) * S_ + nb * 128;
    const int zc4 = (tid & 31) * 4, zr0 = tid >> 5;
    const float4 zf4 = {0.f, 0.f, 0.f, 0.f};

    stage(0, 0);
    __syncthreads();
    for (int kt = 0; kt < KT_; kt++) {
        int cur = kt & 1;
        if (kt + 1 < KT_) stage(cur ^ 1, kt + 1);
        if (kt < 8) *(float4*)(Fb + (size_t)(zr0 + kt * 16) * S_ + zc4) = zf4;
        bf16x8 ah[4], al[4], bh[2];
#pragma unroll
        for (int i = 0; i < 4; i++) {
            int offA = (wr * 4 + i) * 1024 + lane * 16;
            ah[i] = *(const bf16x8*)&lds[cur][0][offA];
            al[i] = *(const bf16x8*)&lds[cur][1][offA];
        }
#pragma unroll
        for (int j = 0; j < 2; j++) {
            int offB = (wc * 2 + j) * 1024 + lane * 16;
            bh[j] = *(const bf16x8*)&lds[cur][2][offB];
        }
#pragma unroll
        for (int i = 0; i < 4; i++)
#pragma unroll
            for (int j = 0; j < 2; j++)
                acc[i][j] = __builtin_amdgcn_mfma_f32_16x16x32_bf16(ah[i], bh[j], acc[i][j], 0, 0, 0);
#pragma unroll
        for (int i = 0; i < 4; i++)
#pragma unroll
            for (int j = 0; j < 2; j++)
                acc[i][j] = __builtin_amdgcn_mfma_f32_16x16x32_bf16(al[i], bh[j], acc[i][j], 0, 0, 0);
        __syncthreads();
    }

    const int col0 = nb * 128 + wc * 32 + (lane & 15);
    const int row0 = mb * 128 + wr * 64 + (lane >> 4) * 4;
    float b1v[2];
    int dd[2];
#pragma unroll
    for (int j = 0; j < 2; j++) {
        b1v[j] = b1[col0 + j * 16];
        dd[j] = (deadf[col0 + j * 16] >= DEAD_THRESH) ? 1 : 0;
    }
    const uint32_t gseg = (uint32_t)(mb * 128 + nb) * 8 + w;
    uint2* segM = glM + (size_t)gseg * CAPSEG_M;
    uint2* segD = glD + (size_t)gseg * CAPSEG_D;
    const uint64_t lmlt = ((uint64_t)1 << lane) - 1;
    uint32_t runM = 0, runD = 0;
#pragma unroll
    for (int i = 0; i < 4; i++)
#pragma unroll
        for (int j = 0; j < 2; j++)
#pragma unroll
            for (int r = 0; r < 4; r++) {
                float v = fmaxf(acc[i][j][r] + b1v[j], 0.0f);
                bool pass = v >= T_LO;
                uint64_t mask = __ballot(pass);
                if (mask) {
                    uint32_t prefix = (uint32_t)__popcll(mask & lmlt);
                    uint2 ent;
                    ent.x = (uint32_t)(row0 + i * 16 + r) * S_ + (uint32_t)(col0 + j * 16);
                    ent.y = __float_as_uint(v);
                    if (pass && runM + prefix < CAPSEG_M) segM[runM + prefix] = ent;
                    runM += (uint32_t)__popcll(mask);
                    bool dp = pass && dd[j];
                    uint64_t dmask = __ballot(dp);
                    if (dmask) {
                        uint32_t dprefix = (uint32_t)__popcll(dmask & lmlt);
                        if (dp && runD + dprefix < CAPSEG_D) segD[runD + dprefix] = ent;
                        runD += (uint32_t)__popcll(dmask);
                    }
                }
            }
    if (lane == 0) {
        bcM[gseg] = runM < CAPSEG_M ? runM : CAPSEG_M;
        bcD[gseg] = runD < CAPSEG_D ? runD : CAPSEG_D;
    }
}

// ---------------- exclusive prefix over segment counts -> offsets + totals --------
__global__ __launch_bounds__(256) void seg_scan_k(const uint32_t* __restrict__ bcM,
                                                  const uint32_t* __restrict__ bcD,
                                                  uint32_t* __restrict__ soM,
                                                  uint32_t* __restrict__ soD,
                                                  uint32_t* __restrict__ cnts) {
    __shared__ uint32_t part[256];
    const int t = threadIdx.x;
    for (int sel = 0; sel < 2; sel++) {
        const uint32_t* bc = sel ? bcD : bcM;
        uint32_t* so = sel ? soD : soM;
        uint32_t s = 0;
        for (int i = 0; i < NSEG / 256; i++) s += bc[t * (NSEG / 256) + i];
        part[t] = s;
        __syncthreads();
        for (int d = 1; d < 256; d <<= 1) {
            uint32_t v = (t >= d) ? part[t - d] : 0;
            __syncthreads();
            part[t] += v;
            __syncthreads();
        }
        uint32_t run = (t == 0) ? 0 : part[t - 1];
        for (int i = 0; i < NSEG / 256; i++) {
            uint32_t c = bc[t * (NSEG / 256) + i];
            so[t * (NSEG / 256) + i] = run;
            run += c;
        }
        if (t == 255) cnts[sel] = run;
        __syncthreads();
    }
}

// ---------------- compact segments to dense lists + histogram, y=0 M / y=1 D ------
__global__ __launch_bounds__(256) void compact_hist_k(const uint2* __restrict__ glM,
                                                      const uint2* __restrict__ glD,
                                                      const uint32_t* __restrict__ bcM,
                                                      const uint32_t* __restrict__ bcD,
                                                      const uint32_t* __restrict__ soM,
                                                      const uint32_t* __restrict__ soD,
                                                      uint2* __restrict__ cmpM,
                                                      uint2* __restrict__ cmpD,
                                                      uint32_t* __restrict__ ghM,
                                                      uint32_t* __restrict__ ghD) {
    __shared__ uint32_t h[NBIN];
    int sel = blockIdx.y;
    const uint2* list = sel ? glD : glM;
    const uint32_t* bc = sel ? bcD : bcM;
    const uint32_t* so = sel ? soD : soM;
    uint2* cmp = sel ? cmpD : cmpM;
    uint32_t cap = sel ? CAPSEG_D : CAPSEG_M;
    uint32_t* gh = sel ? ghD : ghM;
    for (int i = threadIdx.x; i < NBIN; i += 256) h[i] = 0;
    __syncthreads();
    const int wv = threadIdx.x >> 6, lane = threadIdx.x & 63;
    for (uint32_t seg = blockIdx.x * 4 + wv; seg < NSEG; seg += gridDim.x * 4) {
        uint32_t n = bc[seg], off = so[seg];
        for (uint32_t i = lane; i < n; i += 64) {
            uint2 e = list[(size_t)seg * cap + i];
            cmp[off + i] = e;
            atomicAdd(&h[binOf(__uint_as_float(e.y))], 1u);
        }
    }
    __syncthreads();
    for (int i = threadIdx.x; i < NBIN; i += 256)
        if (h[i]) atomicAdd(&gh[i], h[i]);
}

// ---------------- find boundary bin b* (parallel chunked scan) ----------------
__global__ __launch_bounds__(256) void scan_k(const uint32_t* __restrict__ ghM,
                                              const uint32_t* __restrict__ ghD,
                                              uint32_t* __restrict__ scal) {
    __shared__ uint32_t h[NBIN];
    __shared__ uint32_t csum[64];
    for (int sel = 0; sel < 2; sel++) {
        const uint32_t* gh = sel ? ghD : ghM;
        uint32_t need = sel ? NEED_DEAD : NEED_MAIN;
        for (int i = threadIdx.x; i < NBIN; i += 256) h[i] = gh[i];
        __syncthreads();
        if (threadIdx.x < 64) {
            uint32_t s = 0;
#pragma unroll
            for (int j = 0; j < 32; j++) s += h[threadIdx.x * 32 + j];
            csum[threadIdx.x] = s;
        }
        __syncthreads();
        if (threadIdx.x == 0) {
            uint32_t cum = 0; int c = 63;
            for (; c > 0; c--) { uint32_t cc = csum[c]; if (cum + cc >= need) break; cum += cc; }
            int b = c * 32 + 31;
            for (; b > c * 32; b--) { uint32_t cc = h[b]; if (cum + cc >= need) break; cum += cc; }
            uint32_t extra = 0;
            for (int j = b + 1; j < b + REG_W && j < NBIN; j++) extra += h[j];
            scal[sel ? 2 : 0] = (uint32_t)b;
            scal[sel ? 3 : 1] = need - cum + extra;
        }
        __syncthreads();
    }
}

// ------- pull boundary-region (bins b*-REG_W .. b*+REG_W-1) from dense lists --------
// per-thread atomics (compiler wave-coalesces same-address adds)
__global__ __launch_bounds__(256) void bnd_filter_k(const uint2* __restrict__ cmpM,
                                                    const uint2* __restrict__ cmpD,
                                                    const uint32_t* __restrict__ scal,
                                                    uint2* __restrict__ bndM,
                                                    uint2* __restrict__ bndD,
                                                    uint32_t* __restrict__ cnts) {
    int sel = blockIdx.y;
    const uint2* list = sel ? cmpD : cmpM;
    uint2* bnd = sel ? bndD : bndM;
    uint32_t n = cnts[sel];
    uint32_t bs = scal[sel ? 2 : 0];
    for (uint32_t i = blockIdx.x * 256 + threadIdx.x; i < n; i += gridDim.x * 256) {
        uint2 ent = list[i];
        uint32_t bb = binOf(__uint_as_float(ent.y));
        if (bb + REG_W >= bs && bb <= bs + REG_W - 1) {
            uint32_t p = atomicAdd(&cnts[2 + sel], 1u);
            if (p < BNDCAP) bnd[p] = ent;
        }
    }
}

// ---------------- fp64 recompute, wave-per-candidate (4 per block) ----------------
__global__ __launch_bounds__(256) void bnd_f64_k(const uint2* __restrict__ bndM,
                                                 const uint2* __restrict__ bndD,
                                                 const uint32_t* __restrict__ cnts,
                                                 const float* __restrict__ x,
                                                 const float* __restrict__ w1,
                                                 const float* __restrict__ b1,
                                                 const float* __restrict__ b2,
                                                 double* __restrict__ bvM,
                                                 double* __restrict__ bvD) {
    int sel = blockIdx.y;
    const uint2* bnd = sel ? bndD : bndM;
    double* bv64 = sel ? bvD : bvM;
    uint32_t n = cnts[2 + sel]; if (n > BNDCAP) n = BNDCAP;
    uint32_t i = blockIdx.x * 4 + (threadIdx.x >> 6);
    if (i >= n) return;
    const int lane = threadIdx.x & 63;
    uint2 ent = bnd[i];
    uint32_t m = ent.x >> 14, s = ent.x & (S_ - 1);
    const float* xr = x + (size_t)m * H_;
    const float* wr = w1 + (size_t)s * H_;
    double sum = 0.0;
#pragma unroll
    for (int e = 0; e < 8; e++) {
        int k = lane + e * 64;
        sum += ((double)xr[k] - (double)b2[k]) * (double)wr[k];
    }
#pragma unroll
    for (int off = 32; off; off >>= 1) sum += __shfl_down(sum, off, 64);
    if (lane == 0) {
        double tot = sum + (double)b1[s];
        bv64[i] = tot > 0.0 ? tot : 0.0;
    }
}

// ------ exact top-r' in region: O(n) histogram-select + tie rank; DIRECT writes ------
__global__ __launch_bounds__(1024) void rank_hist_k(const uint2* __restrict__ bndM,
                                                    const double* __restrict__ bvM,
                                                    const uint2* __restrict__ bndD,
                                                    const double* __restrict__ bvD,
                                                    uint32_t* __restrict__ cnts,
                                                    const uint32_t* __restrict__ scal,
                                                    float* __restrict__ fsp,
                                                    uint2* __restrict__ entM,
                                                    uint2* __restrict__ entD,
                                                    uint32_t* __restrict__ rcM,
                                                    uint32_t* __restrict__ rcD) {
    int sel = blockIdx.x;
    const uint2* bnd = sel ? bndD : bndM;
    const double* bv = sel ? bvD : bvM;
    uint2* entries = sel ? entD : entM;
    uint32_t* rowCnt = sel ? rcD : rcM;
    const int capRow = sel ? CAPROW_D : CAPROW_M;
    uint32_t n = cnts[2 + sel]; if (n > BNDCAP) n = BNDCAP;
    uint32_t r = scal[sel ? 3 : 1]; if (r > n) r = n;
    uint32_t bs = scal[sel ? 2 : 0];
    uint32_t loBin = bs - (REG_W + PAD_BINS);
    uint32_t hiBin = bs + (REG_W + PAD_BINS);
    double lo = (double)__uint_as_float(BIN_BASE + (loBin << BIN_SHIFT));
    double hi = (double)__uint_as_float(BIN_BASE + (hiBin << BIN_SHIFT));
    double scale = (double)NSUB / (hi - lo);

    __shared__ uint32_t h[NSUB];
    __shared__ uint32_t cs[1024];
    __shared__ uint32_t c2[64];
    __shared__ uint32_t sCb, sAbove, sTieCnt;
    __shared__ double tieV[TIECAP];
    __shared__ uint2 tieE[TIECAP];
    const int t = threadIdx.x;
    for (int i = t; i < NSUB; i += 1024) h[i] = 0;
    if (t == 0) sTieCnt = 0;
    __syncthreads();
    for (uint32_t i = t; i < n; i += 1024) {
        double v = bv[i];
        int k = (int)((v - lo) * scale);
        k = k < 0 ? 0 : (k > NSUB - 1 ? NSUB - 1 : k);
        atomicAdd(&h[k], 1u);
    }
    __syncthreads();
    {
        uint32_t s = 0;
#pragma unroll
        for (int j = 0; j < 8; j++) s += h[t * 8 + j];
        cs[t] = s;
    }
    __syncthreads();
    if (t < 64) {
        uint32_t s = 0;
#pragma unroll
        for (int j = 0; j < 16; j++) s += cs[t * 16 + j];
        c2[t] = s;
    }
    __syncthreads();
    if (t == 0) {
        uint32_t cum = 0; int w2 = 63;
        for (; w2 > 0; w2--) { if (cum + c2[w2] >= r) break; cum += c2[w2]; }
        int c = w2 * 16 + 15;
        for (; c > w2 * 16; c--) { if (cum + cs[c] >= r) break; cum += cs[c]; }
        int b = c * 8 + 7;
        for (; b > c * 8; b--) { if (cum + h[b] >= r) break; cum += h[b]; }
        sCb = (uint32_t)b;
        sAbove = cum;
    }
    __syncthreads();
    const uint32_t cb = sCb;
    uint32_t rr = r - sAbove;
    const int lane = t & 63;
    const uint64_t lmlt = ((uint64_t)1 << lane) - 1;
    for (uint32_t i0 = 0; i0 < n; i0 += 1024) {
        uint32_t i = i0 + t;
        bool valid = i < n;
        double v = valid ? bv[i] : -1.0;
        uint32_t k = 0;
        if (valid) {
            int kk = (int)((v - lo) * scale);
            k = (uint32_t)(kk < 0 ? 0 : (kk > NSUB - 1 ? NSUB - 1 : kk));
        }
        if (valid && k > cb) {
            uint2 ent = bnd[i];
            float fv = __uint_as_float(ent.y);
            if (!sel) fsp[ent.x] = fv;
            uint32_t row = ent.x >> 14;
            uint32_t slot = atomicAdd(&rowCnt[row], 1u);
            if (slot < (uint32_t)capRow)
                entries[(size_t)row * capRow + slot] = make_uint2(ent.x & (S_ - 1), ent.y);
        }
        bool tie = valid && k == cb;
        uint64_t tm = __ballot(tie);
        if (tm) {
            uint32_t base = 0;
            if (lane == 0) base = atomicAdd(&sTieCnt, (uint32_t)__popcll(tm));
            base = __shfl(base, 0, 64);
            if (tie) {
                uint32_t p = base + __popcll(tm & lmlt);
                if (p < TIECAP) { tieV[p] = v; tieE[p] = bnd[i]; }
            }
        }
    }
    __syncthreads();
    uint32_t tc = sTieCnt; if (tc > TIECAP) tc = TIECAP;
    if (rr > tc) rr = tc;
    if (t < (int)tc) {
        double vi = tieV[t]; uint32_t ii = tieE[t].x;
        uint32_t rank = 0;
        for (uint32_t j = 0; j < tc; j++) {
            double vj = tieV[j]; uint32_t ij = tieE[j].x;
            rank += (vj > vi || (vj == vi && ij < ii)) ? 1u : 0u;
        }
        if (rank < rr) {
            uint2 ent = tieE[t];
            float fv = __uint_as_float(ent.y);
            if (!sel) fsp[ent.x] = fv;
            uint32_t row = ent.x >> 14;
            uint32_t slot = atomicAdd(&rowCnt[row], 1u);
            if (slot < (uint32_t)capRow)
                entries[(size_t)row * capRow + slot] = make_uint2(ent.x & (S_ - 1), ent.y);
        }
    }
}

// ---------------- scatter uncond picks (bins >= b*+REG_W) from dense lists ----------
__global__ __launch_bounds__(256) void scatter_list_k(const uint2* __restrict__ cmpM,
                                                      const uint2* __restrict__ cmpD,
                                                      const uint32_t* __restrict__ cnts,
                                                      const uint32_t* __restrict__ scal,
                                                      float* __restrict__ fsp,
                                                      uint2* __restrict__ entM,
                                                      uint2* __restrict__ entD,
                                                      uint32_t* __restrict__ rcM,
                                                      uint32_t* __restrict__ rcD) {
    int sel = blockIdx.y;
    const uint2* list = sel ? cmpD : cmpM;
    uint2* entries = sel ? entD : entM;
    uint32_t* rowCnt = sel ? rcD : rcM;
    int capRow = sel ? CAPROW_D : CAPROW_M;
    uint32_t n = cnts[sel];
    uint32_t bsReg = scal[sel ? 2 : 0] + REG_W - 1;
    for (uint32_t i = blockIdx.x * 256 + threadIdx.x; i < n; i += gridDim.x * 256) {
        uint2 ent = list[i];
        float v = __uint_as_float(ent.y);
        if (binOf(v) <= bsReg) continue;   // region handled by rank_hist_k
        if (!sel) fsp[ent.x] = v;
        uint32_t row = ent.x >> 14;
        uint32_t slot = atomicAdd(&rowCnt[row], 1u);
        if (slot < (uint32_t)capRow)
            entries[(size_t)row * capRow + slot] = make_uint2(ent.x & (S_ - 1), ent.y);
    }
}

// ---------------- sparse decode: x_rec & dead_x (bf16 W2T) ----------------
__global__ __launch_bounds__(512) void decode_k(const uint2* __restrict__ entM,
                                                const uint32_t* __restrict__ rcM,
                                                const uint2* __restrict__ entD,
                                                const uint32_t* __restrict__ rcD,
                                                const uint16_t* __restrict__ W2T,
                                                const float* __restrict__ b2,
                                                float* __restrict__ xrec,
                                                float* __restrict__ deadx) {
    __shared__ uint2 em[CAPROW_M];
    __shared__ uint2 ed[CAPROW_D];
    int b = blockIdx.x, h = threadIdx.x;
    uint32_t nm = rcM[b]; if (nm > CAPROW_M) nm = CAPROW_M;
    uint32_t nd = rcD[b]; if (nd > CAPROW_D) nd = CAPROW_D;
    for (uint32_t i = h; i < nm; i += 512) em[i] = entM[(size_t)b * CAPROW_M + i];
    for (uint32_t i = h; i < nd; i += 512) ed[i] = entD[(size_t)b * CAPROW_D + i];
    __syncthreads();
    float bias = b2[h];
    float a = bias, d = bias;
    for (uint32_t i = 0; i < nm; i++)
        a = fmaf(__uint_as_float(em[i].y), bf2f(W2T[(size_t)em[i].x * H_ + h]), a);
    for (uint32_t i = 0; i < nd; i++)
        d = fmaf(__uint_as_float(ed[i].y), bf2f(W2T[(size_t)ed[i].x * H_ + h]), d);
    xrec[(size_t)b * H_ + h] = a;
    deadx[(size_t)b * H_ + h] = d;
}

extern "C" void kernel_launch(void* const* d_in, const int* in_sizes, int n_in,
                              void* d_out, int out_size, void* d_ws, size_t ws_size,
                              hipStream_t stream) {
    const float* x = (const float*)d_in[0];
    const float* w1 = (const float*)d_in[1];
    const float* b1 = (const float*)d_in[2];
    const float* w2 = (const float*)d_in[3];
    const float* b2 = (const float*)d_in[4];
    const int* deadf = (const int*)d_in[5];

    float* out = (float*)d_out;
    float* xrec = out;
    float* fsp = out + (size_t)B_ * H_;
    float* deadx = out + (size_t)B_ * H_ + (size_t)B_ * S_;

    uint8_t* w = (uint8_t*)d_ws;
    size_t off = 0;
    auto alloc = [&](size_t bytes) { uint8_t* p = w + off; off = (off + bytes + 255) & ~(size_t)255; return p; };

    uint16_t* W2T = (uint16_t*)alloc((size_t)S_ * H_ * 2);
    uint8_t* ctrl = alloc(NBIN * 8 + 128 + (size_t)B_ * 8);
    uint32_t* ghM = (uint32_t*)ctrl;
    uint32_t* ghD = (uint32_t*)(ctrl + NBIN * 4);
    uint32_t* cnts = (uint32_t*)(ctrl + NBIN * 8);         // [0]totM [1]totD [2]bndM [3]bndD
    uint32_t* scal = (uint32_t*)(ctrl + NBIN * 8 + 64);    // [0]bstarM [1]rM [2]bstarD [3]rD
    uint32_t* rcM = (uint32_t*)(ctrl + NBIN * 8 + 128);
    uint32_t* rcD = (uint32_t*)(ctrl + NBIN * 8 + 128 + B_ * 4);
    size_t ctrlBytes = NBIN * 8 + 128 + (size_t)B_ * 8;

    uint2* listM = (uint2*)alloc((size_t)NSEG * CAPSEG_M * 8);
    uint2* listD = (uint2*)alloc((size_t)NSEG * CAPSEG_D * 8);
    uint32_t* bcM = (uint32_t*)alloc((size_t)NSEG * 4);
    uint32_t* bcD = (uint32_t*)alloc((size_t)NSEG * 4);
    uint32_t* soM = (uint32_t*)alloc((size_t)NSEG * 4);
    uint32_t* soD = (uint32_t*)alloc((size_t)NSEG * 4);
    uint2* cmpM = (uint2*)alloc((size_t)NSEG * CAPSEG_M * 8);
    uint2* cmpD = (uint2*)alloc((size_t)NSEG * CAPSEG_D * 8);
    uint2* bndM = (uint2*)alloc((size_t)BNDCAP * 8);
    uint2* bndD = (uint2*)alloc((size_t)BNDCAP * 8);
    double* bvM = (double*)alloc((size_t)BNDCAP * 8);
    double* bvD = (double*)alloc((size_t)BNDCAP * 8);
    uint2* entM = (uint2*)alloc((size_t)B_ * CAPROW_M * 8);
    uint2* entD = (uint2*)alloc((size_t)B_ * CAPROW_D * 8);
    uint8_t* AhT = alloc((size_t)B_ * H_ * 2);
    uint8_t* AlT = alloc((size_t)B_ * H_ * 2);
    uint8_t* WhT = alloc((size_t)S_ * H_ * 2);

    (void)hipMemsetAsync(ctrl, 0, ctrlBytes, stream);
    transpose_k<<<dim3(S_ / 32, H_ / 32), 256, 0, stream>>>(w2, W2T);
    split_all_k<<<5120, 256, 0, stream>>>(x, w1, b2, AhT, AlT, WhT);
    gemm_fused<<<dim3(512, 8), 512, 0, stream>>>(AhT, AlT, WhT, b1, deadf,
                                                 listM, listD, bcM, bcD, fsp);
    seg_scan_k<<<1, 256, 0, stream>>>(bcM, bcD, soM, soD, cnts);
    compact_hist_k<<<dim3(256, 2), 256, 0, stream>>>(listM, listD, bcM, bcD, soM, soD,
                                                     cmpM, cmpD, ghM, ghD);
    scan_k<<<1, 256, 0, stream>>>(ghM, ghD, scal);
    bnd_filter_k<<<dim3(1024, 2), 256, 0, stream>>>(cmpM, cmpD, scal, bndM, bndD, cnts);
    bnd_f64_k<<<dim3(BNDCAP / 4, 2), 256, 0, stream>>>(bndM, bndD, cnts, x, w1, b1, b2, bvM, bvD);
    rank_hist_k<<<2, 1024, 0, stream>>>(bndM, bvM, bndD, bvD, cnts, scal,
                                        fsp, entM, entD, rcM, rcD);
    scatter_list_k<<<dim3(1024, 2), 256, 0, stream>>>(cmpM, cmpD, cnts, scal, fsp,
                                                      entM, entD, rcM, rcD);
    decode_k<<<B_, 512, 0, stream>>>(entM, rcM, entD, rcD, W2T, b2, xrec, deadx);
}

// Round 14
// 465.923 us; speedup vs baseline: 1.3625x; 1.0902x over previous
//
#include <hip/hip_runtime.h>
#include <stdint.h>

#define B_  4096
#define H_  512
#define S_  16384
#define KT_ 16            // H_/32 K-steps of 32
#define NEED_MAIN 131072  // K*B
#define NEED_DEAD 65536   // DEAD_K*B
#define DEAD_THRESH 5

#define T_LO 1.05078125f         // exact bin edge: 0x3F868000
#define BIN_BASE 0x3F800000u
#define BIN_SHIFT 13
#define NBIN 2048                // covers [1.0, 4.0)
#define REG_W 8                  // f64-rescue region = [b*-8, b*+7]; uncond >= b*+8
#define PAD_BINS 2
#define NSUB 8192
#define TIECAP 512

#define NSEG 32768               // 4096 blocks x 8 waves
#define CAPSEG_M 128             // lambda ~21
#define CAPSEG_D 64              // lambda ~10
#define BNDCAP 16384
#define CAPROW_M 192
#define CAPROW_D 128

typedef __bf16 bf16x8 __attribute__((ext_vector_type(8)));
typedef float f32x4 __attribute__((ext_vector_type(4)));
typedef unsigned short ushort8 __attribute__((ext_vector_type(8)));

__device__ __forceinline__ uint32_t binOf(float v) {
    uint32_t b = (__float_as_uint(v) - BIN_BASE) >> BIN_SHIFT;
    return b > (NBIN - 1) ? (NBIN - 1) : b;
}
__device__ __forceinline__ uint16_t f2bf(float f) {
    uint32_t u = __float_as_uint(f);
    uint32_t r = u + 0x7FFFu + ((u >> 16) & 1u);   // RNE
    return (uint16_t)(r >> 16);
}
__device__ __forceinline__ float bf2f(uint16_t b) {
    return __uint_as_float((uint32_t)b << 16);
}
__device__ __forceinline__ void gload16(const void* g, void* l) {
    __builtin_amdgcn_global_load_lds((const __attribute__((address_space(1))) uint32_t*)g,
                                     (__attribute__((address_space(3))) uint32_t*)l, 16, 0, 0);
}

// ------ fused prep: blocks 0..8191 transpose W2->bf16 W2T; 8192..13311 split x/w1 ------
__global__ __launch_bounds__(256) void prep_k(const float* __restrict__ W2,
                                              uint16_t* __restrict__ W2T,
                                              const float* __restrict__ x,
                                              const float* __restrict__ w1,
                                              const float* __restrict__ b2,
                                              uint8_t* __restrict__ AhT,
                                              uint8_t* __restrict__ AlT,
                                              uint8_t* __restrict__ WhT) {
    __shared__ float tile[32][33];
    int b = blockIdx.x;
    if (b < 8192) {
        int s0 = (b & 511) * 32, h0 = (b >> 9) * 32;
        int tx = threadIdx.x & 31, ty = threadIdx.x >> 5;
#pragma unroll
        for (int i = 0; i < 4; i++) {
            int h = h0 + ty + i * 8;
            tile[ty + i * 8][tx] = W2[(size_t)h * S_ + s0 + tx];
        }
        __syncthreads();
#pragma unroll
        for (int i = 0; i < 4; i++) {
            int s = s0 + ty + i * 8;
            W2T[(size_t)s * H_ + h0 + tx] = f2bf(tile[tx][ty + i * 8]);
        }
        return;
    }
    int bb = b - 8192;
    int isX = bb < 1024;
    int tid = (isX ? bb : bb - 1024) * 256 + threadIdx.x;
    int r = tid >> 6, h8 = tid & 63;
    int k0 = h8 << 3;
    const float* src = isX ? x : w1;
    const float* s = src + (size_t)r * H_ + k0;
    float4 v0 = *(const float4*)s, v1 = *(const float4*)(s + 4);
    float a[8] = {v0.x, v0.y, v0.z, v0.w, v1.x, v1.y, v1.z, v1.w};
    if (isX) {
        float4 c0 = *(const float4*)(b2 + k0), c1 = *(const float4*)(b2 + k0 + 4);
        a[0] -= c0.x; a[1] -= c0.y; a[2] -= c0.z; a[3] -= c0.w;
        a[4] -= c1.x; a[5] -= c1.y; a[6] -= c1.z; a[7] -= c1.w;
    }
    ushort8 Hh, Ll;
#pragma unroll
    for (int e = 0; e < 8; e++) {
        uint16_t h = f2bf(a[e]);
        Hh[e] = h;
        Ll[e] = f2bf(a[e] - bf2f(h));
    }
    int rb = r >> 7, kt = k0 >> 5;
    int mf = (r >> 4) & 7;
    int ln = (r & 15) | (((k0 >> 3) & 3) << 4);
    size_t byte = ((size_t)rb * KT_ + kt) * 8192 + (size_t)mf * 1024 + (size_t)ln * 16;
    if (isX) {
        *(ushort8*)(AhT + byte) = Hh;
        *(ushort8*)(AlT + byte) = Ll;
    } else {
        *(ushort8*)(WhT + byte) = Hh;
    }
}

// ------- f = relu((x-b2)@W1^T + b1) via 2x bf16 MFMA, 8 waves of 64x32, collect ------
__global__ __launch_bounds__(512) void gemm_fused(const uint8_t* __restrict__ AhT,
                                                  const uint8_t* __restrict__ AlT,
                                                  const uint8_t* __restrict__ WhT,
                                                  const float* __restrict__ b1,
                                                  const int* __restrict__ deadf,
                                                  uint2* __restrict__ glM,
                                                  uint2* __restrict__ glD,
                                                  uint32_t* __restrict__ bcM,
                                                  uint32_t* __restrict__ bcD,
                                                  float* __restrict__ fsp) {
    __shared__ uint8_t lds[2][3][8192];   // [buf][Ah,Al,Wh][tile]
    const int tid = threadIdx.x;
    const int lane = tid & 63, w = tid >> 6;     // 8 waves
    const int wr = w >> 2, wc = w & 3;           // wave tile 64x32
    const int lin = blockIdx.y * 512 + blockIdx.x;
    const int xcd = lin & 7, idx = lin >> 3;
    const int mb = xcd * 4 + (idx & 3), nb = idx >> 2;   // mb-fastest within XCD

    const uint8_t* gAh = AhT + (size_t)mb * KT_ * 8192;
    const uint8_t* gAl = AlT + (size_t)mb * KT_ * 8192;
    const uint8_t* gBh = WhT + (size_t)nb * KT_ * 8192;

    f32x4 acc[4][2];
#pragma unroll
    for (int i = 0; i < 4; i++)
#pragma unroll
        for (int j = 0; j < 2; j++) acc[i][j] = (f32x4){0.f, 0.f, 0.f, 0.f};

    auto stage = [&](int buf, int kt) {
        size_t tb = (size_t)kt * 8192;
        int o = tid * 16;
        gload16(gAh + tb + o, &lds[buf][0][o]);
        gload16(gAl + tb + o, &lds[buf][1][o]);
        gload16(gBh + tb + o, &lds[buf][2][o]);
    };

    float* Fb = fsp + (size_t)(mb * 128) * S_ + nb * 128;
    const int zc4 = (tid & 31) * 4, zr0 = tid >> 5;
    const f32x4 zf4 = {0.f, 0.f, 0.f, 0.f};

    stage(0, 0);
    __syncthreads();
    for (int kt = 0; kt < KT_; kt++) {
        int cur = kt & 1;
        if (kt + 1 < KT_) stage(cur ^ 1, kt + 1);
        if (kt < 8)
            __builtin_nontemporal_store(zf4, (f32x4*)(Fb + (size_t)(zr0 + kt * 16) * S_ + zc4));
        bf16x8 ah[4], al[4], bh[2];
#pragma unroll
        for (int i = 0; i < 4; i++) {
            int offA = (wr * 4 + i) * 1024 + lane * 16;
            ah[i] = *(const bf16x8*)&lds[cur][0][offA];
            al[i] = *(const bf16x8*)&lds[cur][1][offA];
        }
#pragma unroll
        for (int j = 0; j < 2; j++) {
            int offB = (wc * 2 + j) * 1024 + lane * 16;
            bh[j] = *(const bf16x8*)&lds[cur][2][offB];
        }
#pragma unroll
        for (int i = 0; i < 4; i++)
#pragma unroll
            for (int j = 0; j < 2; j++)
                acc[i][j] = __builtin_amdgcn_mfma_f32_16x16x32_bf16(ah[i], bh[j], acc[i][j], 0, 0, 0);
#pragma unroll
        for (int i = 0; i < 4; i++)
#pragma unroll
            for (int j = 0; j < 2; j++)
                acc[i][j] = __builtin_amdgcn_mfma_f32_16x16x32_bf16(al[i], bh[j], acc[i][j], 0, 0, 0);
        __syncthreads();
    }

    const int col0 = nb * 128 + wc * 32 + (lane & 15);
    const int row0 = mb * 128 + wr * 64 + (lane >> 4) * 4;
    float b1v[2];
    int dd[2];
#pragma unroll
    for (int j = 0; j < 2; j++) {
        b1v[j] = b1[col0 + j * 16];
        dd[j] = (deadf[col0 + j * 16] >= DEAD_THRESH) ? 1 : 0;
    }
    const uint32_t gseg = (uint32_t)(mb * 128 + nb) * 8 + w;
    uint2* segM = glM + (size_t)gseg * CAPSEG_M;
    uint2* segD = glD + (size_t)gseg * CAPSEG_D;
    const uint64_t lmlt = ((uint64_t)1 << lane) - 1;
    uint32_t runM = 0, runD = 0;
#pragma unroll
    for (int i = 0; i < 4; i++)
#pragma unroll
        for (int j = 0; j < 2; j++)
#pragma unroll
            for (int r = 0; r < 4; r++) {
                float v = fmaxf(acc[i][j][r] + b1v[j], 0.0f);
                bool pass = v >= T_LO;
                uint64_t mask = __ballot(pass);
                if (mask) {
                    uint32_t prefix = (uint32_t)__popcll(mask & lmlt);
                    uint2 ent;
                    ent.x = (uint32_t)(row0 + i * 16 + r) * S_ + (uint32_t)(col0 + j * 16);
                    ent.y = __float_as_uint(v);
                    if (pass && runM + prefix < CAPSEG_M) segM[runM + prefix] = ent;
                    runM += (uint32_t)__popcll(mask);
                    bool dp = pass && dd[j];
                    uint64_t dmask = __ballot(dp);
                    if (dmask) {
                        uint32_t dprefix = (uint32_t)__popcll(dmask & lmlt);
                        if (dp && runD + dprefix < CAPSEG_D) segD[runD + dprefix] = ent;
                        runD += (uint32_t)__popcll(dmask);
                    }
                }
            }
    if (lane == 0) {
        bcM[gseg] = runM < CAPSEG_M ? runM : CAPSEG_M;
        bcD[gseg] = runD < CAPSEG_D ? runD : CAPSEG_D;
    }
}

// -------- parallel exclusive prefix over 32768 segment counts (1024 thr, uint4) ------
__global__ __launch_bounds__(1024) void seg_scan_k(const uint32_t* __restrict__ bcM,
                                                   const uint32_t* __restrict__ bcD,
                                                   uint32_t* __restrict__ soM,
                                                   uint32_t* __restrict__ soD,
                                                   uint32_t* __restrict__ cnts) {
    __shared__ uint32_t part[1024];
    const int t = threadIdx.x;
    for (int sel = 0; sel < 2; sel++) {
        const uint32_t* bc = sel ? bcD : bcM;
        uint32_t* so = sel ? soD : soM;
        const uint4* b4 = (const uint4*)(bc + t * 32);
        uint32_t s = 0;
#pragma unroll
        for (int i = 0; i < 8; i++) {
            uint4 v = b4[i];
            s += v.x + v.y + v.z + v.w;
        }
        part[t] = s;
        __syncthreads();
        for (int d = 1; d < 1024; d <<= 1) {
            uint32_t v = (t >= d) ? part[t - d] : 0;
            __syncthreads();
            part[t] += v;
            __syncthreads();
        }
        uint32_t run = (t == 0) ? 0 : part[t - 1];
        uint4* so4 = (uint4*)(so + t * 32);
#pragma unroll
        for (int i = 0; i < 8; i++) {
            uint4 v = b4[i];
            uint4 o;
            o.x = run; run += v.x;
            o.y = run; run += v.y;
            o.z = run; run += v.z;
            o.w = run; run += v.w;
            so4[i] = o;
        }
        if (t == 1023) cnts[sel] = run;
        __syncthreads();
    }
}

// ---------------- compact segments to dense lists + histogram, y=0 M / y=1 D ------
__global__ __launch_bounds__(256) void compact_hist_k(const uint2* __restrict__ glM,
                                                      const uint2* __restrict__ glD,
                                                      const uint32_t* __restrict__ bcM,
                                                      const uint32_t* __restrict__ bcD,
                                                      const uint32_t* __restrict__ soM,
                                                      const uint32_t* __restrict__ soD,
                                                      uint2* __restrict__ cmpM,
                                                      uint2* __restrict__ cmpD,
                                                      uint32_t* __restrict__ ghM,
                                                      uint32_t* __restrict__ ghD) {
    __shared__ uint32_t h[NBIN];
    int sel = blockIdx.y;
    const uint2* list = sel ? glD : glM;
    const uint32_t* bc = sel ? bcD : bcM;
    const uint32_t* so = sel ? soD : soM;
    uint2* cmp = sel ? cmpD : cmpM;
    uint32_t cap = sel ? CAPSEG_D : CAPSEG_M;
    uint32_t* gh = sel ? ghD : ghM;
    for (int i = threadIdx.x; i < NBIN; i += 256) h[i] = 0;
    __syncthreads();
    const int wv = threadIdx.x >> 6, lane = threadIdx.x & 63;
    for (uint32_t seg = blockIdx.x * 4 + wv; seg < NSEG; seg += gridDim.x * 4) {
        uint32_t n = bc[seg], off = so[seg];
        for (uint32_t i = lane; i < n; i += 64) {
            uint2 e = list[(size_t)seg * cap + i];
            cmp[off + i] = e;
            atomicAdd(&h[binOf(__uint_as_float(e.y))], 1u);
        }
    }
    __syncthreads();
    for (int i = threadIdx.x; i < NBIN; i += 256)
        if (h[i]) atomicAdd(&gh[i], h[i]);
}

// ---------------- find boundary bin b* (parallel chunked scan) ----------------
__global__ __launch_bounds__(256) void scan_k(const uint32_t* __restrict__ ghM,
                                              const uint32_t* __restrict__ ghD,
                                              uint32_t* __restrict__ scal) {
    __shared__ uint32_t h[NBIN];
    __shared__ uint32_t csum[64];
    for (int sel = 0; sel < 2; sel++) {
        const uint32_t* gh = sel ? ghD : ghM;
        uint32_t need = sel ? NEED_DEAD : NEED_MAIN;
        for (int i = threadIdx.x; i < NBIN; i += 256) h[i] = gh[i];
        __syncthreads();
        if (threadIdx.x < 64) {
            uint32_t s = 0;
#pragma unroll
            for (int j = 0; j < 32; j++) s += h[threadIdx.x * 32 + j];
            csum[threadIdx.x] = s;
        }
        __syncthreads();
        if (threadIdx.x == 0) {
            uint32_t cum = 0; int c = 63;
            for (; c > 0; c--) { uint32_t cc = csum[c]; if (cum + cc >= need) break; cum += cc; }
            int b = c * 32 + 31;
            for (; b > c * 32; b--) { uint32_t cc = h[b]; if (cum + cc >= need) break; cum += cc; }
            uint32_t extra = 0;
            for (int j = b + 1; j < b + REG_W && j < NBIN; j++) extra += h[j];
            scal[sel ? 2 : 0] = (uint32_t)b;
            scal[sel ? 3 : 1] = need - cum + extra;
        }
        __syncthreads();
    }
}

// ------- pull boundary-region (bins b*-REG_W .. b*+REG_W-1) from dense lists --------
__global__ __launch_bounds__(256) void bnd_filter_k(const uint2* __restrict__ cmpM,
                                                    const uint2* __restrict__ cmpD,
                                                    const uint32_t* __restrict__ scal,
                                                    uint2* __restrict__ bndM,
                                                    uint2* __restrict__ bndD,
                                                    uint32_t* __restrict__ cnts) {
    int sel = blockIdx.y;
    const uint2* list = sel ? cmpD : cmpM;
    uint2* bnd = sel ? bndD : bndM;
    uint32_t n = cnts[sel];
    uint32_t bs = scal[sel ? 2 : 0];
    for (uint32_t i = blockIdx.x * 256 + threadIdx.x; i < n; i += gridDim.x * 256) {
        uint2 ent = list[i];
        uint32_t bb = binOf(__uint_as_float(ent.y));
        if (bb + REG_W >= bs && bb <= bs + REG_W - 1) {
            uint32_t p = atomicAdd(&cnts[2 + sel], 1u);
            if (p < BNDCAP) bnd[p] = ent;
        }
    }
}

// ---------------- fp64 recompute, wave-per-candidate (4 per block) ----------------
__global__ __launch_bounds__(256) void bnd_f64_k(const uint2* __restrict__ bndM,
                                                 const uint2* __restrict__ bndD,
                                                 const uint32_t* __restrict__ cnts,
                                                 const float* __restrict__ x,
                                                 const float* __restrict__ w1,
                                                 const float* __restrict__ b1,
                                                 const float* __restrict__ b2,
                                                 double* __restrict__ bvM,
                                                 double* __restrict__ bvD) {
    int sel = blockIdx.y;
    const uint2* bnd = sel ? bndD : bndM;
    double* bv64 = sel ? bvD : bvM;
    uint32_t n = cnts[2 + sel]; if (n > BNDCAP) n = BNDCAP;
    uint32_t i = blockIdx.x * 4 + (threadIdx.x >> 6);
    if (i >= n) return;
    const int lane = threadIdx.x & 63;
    uint2 ent = bnd[i];
    uint32_t m = ent.x >> 14, s = ent.x & (S_ - 1);
    const float* xr = x + (size_t)m * H_;
    const float* wr = w1 + (size_t)s * H_;
    double sum = 0.0;
#pragma unroll
    for (int e = 0; e < 8; e++) {
        int k = lane + e * 64;
        sum += ((double)xr[k] - (double)b2[k]) * (double)wr[k];
    }
#pragma unroll
    for (int off = 32; off; off >>= 1) sum += __shfl_down(sum, off, 64);
    if (lane == 0) {
        double tot = sum + (double)b1[s];
        bv64[i] = tot > 0.0 ? tot : 0.0;
    }
}

// ------ exact top-r' in region: O(n) histogram-select + tie rank; DIRECT writes ------
__global__ __launch_bounds__(1024) void rank_hist_k(const uint2* __restrict__ bndM,
                                                    const double* __restrict__ bvM,
                                                    const uint2* __restrict__ bndD,
                                                    const double* __restrict__ bvD,
                                                    uint32_t* __restrict__ cnts,
                                                    const uint32_t* __restrict__ scal,
                                                    float* __restrict__ fsp,
                                                    uint2* __restrict__ entM,
                                                    uint2* __restrict__ entD,
                                                    uint32_t* __restrict__ rcM,
                                                    uint32_t* __restrict__ rcD) {
    int sel = blockIdx.x;
    const uint2* bnd = sel ? bndD : bndM;
    const double* bv = sel ? bvD : bvM;
    uint2* entries = sel ? entD : entM;
    uint32_t* rowCnt = sel ? rcD : rcM;
    const int capRow = sel ? CAPROW_D : CAPROW_M;
    uint32_t n = cnts[2 + sel]; if (n > BNDCAP) n = BNDCAP;
    uint32_t r = scal[sel ? 3 : 1]; if (r > n) r = n;
    uint32_t bs = scal[sel ? 2 : 0];
    uint32_t loBin = bs - (REG_W + PAD_BINS);
    uint32_t hiBin = bs + (REG_W + PAD_BINS);
    double lo = (double)__uint_as_float(BIN_BASE + (loBin << BIN_SHIFT));
    double hi = (double)__uint_as_float(BIN_BASE + (hiBin << BIN_SHIFT));
    double scale = (double)NSUB / (hi - lo);

    __shared__ uint32_t h[NSUB];
    __shared__ uint32_t cs[1024];
    __shared__ uint32_t c2[64];
    __shared__ uint32_t sCb, sAbove, sTieCnt;
    __shared__ double tieV[TIECAP];
    __shared__ uint2 tieE[TIECAP];
    const int t = threadIdx.x;
    for (int i = t; i < NSUB; i += 1024) h[i] = 0;
    if (t == 0) sTieCnt = 0;
    __syncthreads();
    for (uint32_t i = t; i < n; i += 1024) {
        double v = bv[i];
        int k = (int)((v - lo) * scale);
        k = k < 0 ? 0 : (k > NSUB - 1 ? NSUB - 1 : k);
        atomicAdd(&h[k], 1u);
    }
    __syncthreads();
    {
        uint32_t s = 0;
#pragma unroll
        for (int j = 0; j < 8; j++) s += h[t * 8 + j];
        cs[t] = s;
    }
    __syncthreads();
    if (t < 64) {
        uint32_t s = 0;
#pragma unroll
        for (int j = 0; j < 16; j++) s += cs[t * 16 + j];
        c2[t] = s;
    }
    __syncthreads();
    if (t == 0) {
        uint32_t cum = 0; int w2 = 63;
        for (; w2 > 0; w2--) { if (cum + c2[w2] >= r) break; cum += c2[w2]; }
        int c = w2 * 16 + 15;
        for (; c > w2 * 16; c--) { if (cum + cs[c] >= r) break; cum += cs[c]; }
        int b = c * 8 + 7;
        for (; b > c * 8; b--) { if (cum + h[b] >= r) break; cum += h[b]; }
        sCb = (uint32_t)b;
        sAbove = cum;
    }
    __syncthreads();
    const uint32_t cb = sCb;
    uint32_t rr = r - sAbove;
    const int lane = t & 63;
    const uint64_t lmlt = ((uint64_t)1 << lane) - 1;
    for (uint32_t i0 = 0; i0 < n; i0 += 1024) {
        uint32_t i = i0 + t;
        bool valid = i < n;
        double v = valid ? bv[i] : -1.0;
        uint32_t k = 0;
        if (valid) {
            int kk = (int)((v - lo) * scale);
            k = (uint32_t)(kk < 0 ? 0 : (kk > NSUB - 1 ? NSUB - 1 : kk));
        }
        if (valid && k > cb) {
            uint2 ent = bnd[i];
            float fv = __uint_as_float(ent.y);
            if (!sel) fsp[ent.x] = fv;
            uint32_t row = ent.x >> 14;
            uint32_t slot = atomicAdd(&rowCnt[row], 1u);
            if (slot < (uint32_t)capRow)
                entries[(size_t)row * capRow + slot] = make_uint2(ent.x & (S_ - 1), ent.y);
        }
        bool tie = valid && k == cb;
        uint64_t tm = __ballot(tie);
        if (tm) {
            uint32_t base = 0;
            if (lane == 0) base = atomicAdd(&sTieCnt, (uint32_t)__popcll(tm));
            base = __shfl(base, 0, 64);
            if (tie) {
                uint32_t p = base + __popcll(tm & lmlt);
                if (p < TIECAP) { tieV[p] = v; tieE[p] = bnd[i]; }
            }
        }
    }
    __syncthreads();
    uint32_t tc = sTieCnt; if (tc > TIECAP) tc = TIECAP;
    if (rr > tc) rr = tc;
    if (t < (int)tc) {
        double vi = tieV[t]; uint32_t ii = tieE[t].x;
        uint32_t rank = 0;
        for (uint32_t j = 0; j < tc; j++) {
            double vj = tieV[j]; uint32_t ij = tieE[j].x;
            rank += (vj > vi || (vj == vi && ij < ii)) ? 1u : 0u;
        }
        if (rank < rr) {
            uint2 ent = tieE[t];
            float fv = __uint_as_float(ent.y);
            if (!sel) fsp[ent.x] = fv;
            uint32_t row = ent.x >> 14;
            uint32_t slot = atomicAdd(&rowCnt[row], 1u);
            if (slot < (uint32_t)capRow)
                entries[(size_t)row * capRow + slot] = make_uint2(ent.x & (S_ - 1), ent.y);
        }
    }
}

// ---------------- scatter uncond picks (bins >= b*+REG_W) from dense lists ----------
__global__ __launch_bounds__(256) void scatter_list_k(const uint2* __restrict__ cmpM,
                                                      const uint2* __restrict__ cmpD,
                                                      const uint32_t* __restrict__ cnts,
                                                      const uint32_t* __restrict__ scal,
                                                      float* __restrict__ fsp,
                                                      uint2* __restrict__ entM,
                                                      uint2* __restrict__ entD,
                                                      uint32_t* __restrict__ rcM,
                                                      uint32_t* __restrict__ rcD) {
    int sel = blockIdx.y;
    const uint2* list = sel ? cmpD : cmpM;
    uint2* entries = sel ? entD : entM;
    uint32_t* rowCnt = sel ? rcD : rcM;
    int capRow = sel ? CAPROW_D : CAPROW_M;
    uint32_t n = cnts[sel];
    uint32_t bsReg = scal[sel ? 2 : 0] + REG_W - 1;
    for (uint32_t i = blockIdx.x * 256 + threadIdx.x; i < n; i += gridDim.x * 256) {
        uint2 ent = list[i];
        float v = __uint_as_float(ent.y);
        if (binOf(v) <= bsReg) continue;   // region handled by rank_hist_k
        if (!sel) fsp[ent.x] = v;
        uint32_t row = ent.x >> 14;
        uint32_t slot = atomicAdd(&rowCnt[row], 1u);
        if (slot < (uint32_t)capRow)
            entries[(size_t)row * capRow + slot] = make_uint2(ent.x & (S_ - 1), ent.y);
    }
}

// ---------------- sparse decode: x_rec & dead_x (bf16 W2T) ----------------
__global__ __launch_bounds__(512) void decode_k(const uint2* __restrict__ entM,
                                                const uint32_t* __restrict__ rcM,
                                                const uint2* __restrict__ entD,
                                                const uint32_t* __restrict__ rcD,
                                                const uint16_t* __restrict__ W2T,
                                                const float* __restrict__ b2,
                                                float* __restrict__ xrec,
                                                float* __restrict__ deadx) {
    __shared__ uint2 em[CAPROW_M];
    __shared__ uint2 ed[CAPROW_D];
    int b = blockIdx.x, h = threadIdx.x;
    uint32_t nm = rcM[b]; if (nm > CAPROW_M) nm = CAPROW_M;
    uint32_t nd = rcD[b]; if (nd > CAPROW_D) nd = CAPROW_D;
    for (uint32_t i = h; i < nm; i += 512) em[i] = entM[(size_t)b * CAPROW_M + i];
    for (uint32_t i = h; i < nd; i += 512) ed[i] = entD[(size_t)b * CAPROW_D + i];
    __syncthreads();
    float bias = b2[h];
    float a = bias, d = bias;
    for (uint32_t i = 0; i < nm; i++)
        a = fmaf(__uint_as_float(em[i].y), bf2f(W2T[(size_t)em[i].x * H_ + h]), a);
    for (uint32_t i = 0; i < nd; i++)
        d = fmaf(__uint_as_float(ed[i].y), bf2f(W2T[(size_t)ed[i].x * H_ + h]), d);
    xrec[(size_t)b * H_ + h] = a;
    deadx[(size_t)b * H_ + h] = d;
}

extern "C" void kernel_launch(void* const* d_in, const int* in_sizes, int n_in,
                              void* d_out, int out_size, void* d_ws, size_t ws_size,
                              hipStream_t stream) {
    const float* x = (const float*)d_in[0];
    const float* w1 = (const float*)d_in[1];
    const float* b1 = (const float*)d_in[2];
    const float* w2 = (const float*)d_in[3];
    const float* b2 = (const float*)d_in[4];
    const int* deadf = (const int*)d_in[5];

    float* out = (float*)d_out;
    float* xrec = out;
    float* fsp = out + (size_t)B_ * H_;
    float* deadx = out + (size_t)B_ * H_ + (size_t)B_ * S_;

    uint8_t* w = (uint8_t*)d_ws;
    size_t off = 0;
    auto alloc = [&](size_t bytes) { uint8_t* p = w + off; off = (off + bytes + 255) & ~(size_t)255; return p; };

    uint16_t* W2T = (uint16_t*)alloc((size_t)S_ * H_ * 2);
    uint8_t* ctrl = alloc(NBIN * 8 + 128 + (size_t)B_ * 8);
    uint32_t* ghM = (uint32_t*)ctrl;
    uint32_t* ghD = (uint32_t*)(ctrl + NBIN * 4);
    uint32_t* cnts = (uint32_t*)(ctrl + NBIN * 8);         // [0]totM [1]totD [2]bndM [3]bndD
    uint32_t* scal = (uint32_t*)(ctrl + NBIN * 8 + 64);    // [0]bstarM [1]rM [2]bstarD [3]rD
    uint32_t* rcM = (uint32_t*)(ctrl + NBIN * 8 + 128);
    uint32_t* rcD = (uint32_t*)(ctrl + NBIN * 8 + 128 + B_ * 4);
    size_t ctrlBytes = NBIN * 8 + 128 + (size_t)B_ * 8;

    uint2* listM = (uint2*)alloc((size_t)NSEG * CAPSEG_M * 8);
    uint2* listD = (uint2*)alloc((size_t)NSEG * CAPSEG_D * 8);
    uint32_t* bcM = (uint32_t*)alloc((size_t)NSEG * 4);
    uint32_t* bcD = (uint32_t*)alloc((size_t)NSEG * 4);
    uint32_t* soM = (uint32_t*)alloc((size_t)NSEG * 4);
    uint32_t* soD = (uint32_t*)alloc((size_t)NSEG * 4);
    uint2* cmpM = (uint2*)alloc((size_t)NSEG * CAPSEG_M * 8);
    uint2* cmpD = (uint2*)alloc((size_t)NSEG * CAPSEG_D * 8);
    uint2* bndM = (uint2*)alloc((size_t)BNDCAP * 8);
    uint2* bndD = (uint2*)alloc((size_t)BNDCAP * 8);
    double* bvM = (double*)alloc((size_t)BNDCAP * 8);
    double* bvD = (double*)alloc((size_t)BNDCAP * 8);
    uint2* entM = (uint2*)alloc((size_t)B_ * CAPROW_M * 8);
    uint2* entD = (uint2*)alloc((size_t)B_ * CAPROW_D * 8);
    uint8_t* AhT = alloc((size_t)B_ * H_ * 2);
    uint8_t* AlT = alloc((size_t)B_ * H_ * 2);
    uint8_t* WhT = alloc((size_t)S_ * H_ * 2);

    (void)hipMemsetAsync(ctrl, 0, ctrlBytes, stream);
    prep_k<<<13312, 256, 0, stream>>>(w2, W2T, x, w1, b2, AhT, AlT, WhT);
    gemm_fused<<<dim3(512, 8), 512, 0, stream>>>(AhT, AlT, WhT, b1, deadf,
                                                 listM, listD, bcM, bcD, fsp);
    seg_scan_k<<<1, 1024, 0, stream>>>(bcM, bcD, soM, soD, cnts);
    compact_hist_k<<<dim3(1024, 2), 256, 0, stream>>>(listM, listD, bcM, bcD, soM, soD,
                                                      cmpM, cmpD, ghM, ghD);
    scan_k<<<1, 256, 0, stream>>>(ghM, ghD, scal);
    bnd_filter_k<<<dim3(1024, 2), 256, 0, stream>>>(cmpM, cmpD, scal, bndM, bndD, cnts);
    bnd_f64_k<<<dim3(BNDCAP / 4, 2), 256, 0, stream>>>(bndM, bndD, cnts, x, w1, b1, b2, bvM, bvD);
    rank_hist_k<<<2, 1024, 0, stream>>>(bndM, bvM, bndD, bvD, cnts, scal,
                                        fsp, entM, entD, rcM, rcD);
    scatter_list_k<<<dim3(1024, 2), 256, 0, stream>>>(cmpM, cmpD, cnts, scal, fsp,
                                                      entM, entD, rcM, rcD);
    decode_k<<<B_, 512, 0, stream>>>(entM, rcM, entD, rcD, W2T, b2, xrec, deadx);
}

// Round 15
// 424.031 us; speedup vs baseline: 1.4971x; 1.0988x over previous
//
#include <hip/hip_runtime.h>
#include <stdint.h>

#define B_  4096
#define H_  512
#define S_  16384
#define KT_ 16            // H_/32 K-steps of 32
#define NEED_MAIN 131072  // K*B
#define NEED_DEAD 65536   // DEAD_K*B
#define DEAD_THRESH 5

#define T_LO 1.05078125f         // exact bin edge: 0x3F868000
#define BIN_BASE 0x3F800000u
#define BIN_SHIFT 13
#define NBIN 2048                // covers [1.0, 4.0)
#define REG_W 8                  // f64-rescue region = [b*-8, b*+7]; uncond >= b*+8
#define PAD_BINS 8               // 1-term gemm: f64 drift up to ~5 bins
#define NSUB 8192
#define TIECAP 512

#define NSEG 32768               // 4096 blocks x 8 waves
#define CAPSEG_M 128             // lambda ~21
#define CAPSEG_D 64              // lambda ~10
#define BNDCAP 16384
#define CAPROW_M 192
#define CAPROW_D 128

typedef __bf16 bf16x8 __attribute__((ext_vector_type(8)));
typedef float f32x4 __attribute__((ext_vector_type(4)));
typedef unsigned short ushort8 __attribute__((ext_vector_type(8)));

__device__ __forceinline__ uint32_t binOf(float v) {
    uint32_t b = (__float_as_uint(v) - BIN_BASE) >> BIN_SHIFT;
    return b > (NBIN - 1) ? (NBIN - 1) : b;
}
__device__ __forceinline__ uint16_t f2bf(float f) {
    uint32_t u = __float_as_uint(f);
    uint32_t r = u + 0x7FFFu + ((u >> 16) & 1u);   // RNE
    return (uint16_t)(r >> 16);
}
__device__ __forceinline__ float bf2f(uint16_t b) {
    return __uint_as_float((uint32_t)b << 16);
}
__device__ __forceinline__ void gload16(const void* g, void* l) {
    __builtin_amdgcn_global_load_lds((const __attribute__((address_space(1))) uint32_t*)g,
                                     (__attribute__((address_space(3))) uint32_t*)l, 16, 0, 0);
}

// ------ fused prep: blocks 0..8191 transpose W2->bf16 W2T; 8192..13311 split x/w1 ------
// 1-term gemm: only hi-bf16 parts are stored (AhT for x-b2, WhT for w1).
__global__ __launch_bounds__(256) void prep_k(const float* __restrict__ W2,
                                              uint16_t* __restrict__ W2T,
                                              const float* __restrict__ x,
                                              const float* __restrict__ w1,
                                              const float* __restrict__ b2,
                                              uint8_t* __restrict__ AhT,
                                              uint8_t* __restrict__ WhT) {
    __shared__ float tile[32][33];
    int b = blockIdx.x;
    if (b < 8192) {
        int s0 = (b & 511) * 32, h0 = (b >> 9) * 32;
        int tx = threadIdx.x & 31, ty = threadIdx.x >> 5;
#pragma unroll
        for (int i = 0; i < 4; i++) {
            int h = h0 + ty + i * 8;
            tile[ty + i * 8][tx] = W2[(size_t)h * S_ + s0 + tx];
        }
        __syncthreads();
#pragma unroll
        for (int i = 0; i < 4; i++) {
            int s = s0 + ty + i * 8;
            W2T[(size_t)s * H_ + h0 + tx] = f2bf(tile[tx][ty + i * 8]);
        }
        return;
    }
    int bb = b - 8192;
    int isX = bb < 1024;
    int tid = (isX ? bb : bb - 1024) * 256 + threadIdx.x;
    int r = tid >> 6, h8 = tid & 63;
    int k0 = h8 << 3;
    const float* src = isX ? x : w1;
    const float* s = src + (size_t)r * H_ + k0;
    float4 v0 = *(const float4*)s, v1 = *(const float4*)(s + 4);
    float a[8] = {v0.x, v0.y, v0.z, v0.w, v1.x, v1.y, v1.z, v1.w};
    if (isX) {
        float4 c0 = *(const float4*)(b2 + k0), c1 = *(const float4*)(b2 + k0 + 4);
        a[0] -= c0.x; a[1] -= c0.y; a[2] -= c0.z; a[3] -= c0.w;
        a[4] -= c1.x; a[5] -= c1.y; a[6] -= c1.z; a[7] -= c1.w;
    }
    ushort8 Hh;
#pragma unroll
    for (int e = 0; e < 8; e++) Hh[e] = f2bf(a[e]);
    int rb = r >> 7, kt = k0 >> 5;
    int mf = (r >> 4) & 7;
    int ln = (r & 15) | (((k0 >> 3) & 3) << 4);
    size_t byte = ((size_t)rb * KT_ + kt) * 8192 + (size_t)mf * 1024 + (size_t)ln * 16;
    if (isX) *(ushort8*)(AhT + byte) = Hh;
    else     *(ushort8*)(WhT + byte) = Hh;
}

// ------- f = relu((x-b2)@W1^T + b1) via 1x bf16 MFMA, 8 waves of 64x32, collect ------
// 32KB LDS. Errors vs f64 handled by REG_W=8 rescue region + f64 rerank downstream.
__global__ __launch_bounds__(512) void gemm_fused(const uint8_t* __restrict__ AhT,
                                                  const uint8_t* __restrict__ WhT,
                                                  const float* __restrict__ b1,
                                                  const int* __restrict__ deadf,
                                                  uint2* __restrict__ glM,
                                                  uint2* __restrict__ glD,
                                                  uint32_t* __restrict__ bcM,
                                                  uint32_t* __restrict__ bcD,
                                                  float* __restrict__ fsp) {
    __shared__ uint8_t lds[2][2][8192];   // [buf][Ah,Wh][tile]
    const int tid = threadIdx.x;
    const int lane = tid & 63, w = tid >> 6;     // 8 waves
    const int wr = w >> 2, wc = w & 3;           // wave tile 64x32
    const int lin = blockIdx.y * 512 + blockIdx.x;
    const int xcd = lin & 7, idx = lin >> 3;
    const int mb = xcd * 4 + (idx & 3), nb = idx >> 2;   // mb-fastest within XCD

    const uint8_t* gAh = AhT + (size_t)mb * KT_ * 8192;
    const uint8_t* gBh = WhT + (size_t)nb * KT_ * 8192;

    f32x4 acc[4][2];
#pragma unroll
    for (int i = 0; i < 4; i++)
#pragma unroll
        for (int j = 0; j < 2; j++) acc[i][j] = (f32x4){0.f, 0.f, 0.f, 0.f};

    auto stage = [&](int buf, int kt) {
        size_t tb = (size_t)kt * 8192;
        int o = tid * 16;
        gload16(gAh + tb + o, &lds[buf][0][o]);
        gload16(gBh + tb + o, &lds[buf][1][o]);
    };

    float* Fb = fsp + (size_t)(mb * 128) * S_ + nb * 128;
    const int zc4 = (tid & 31) * 4, zr0 = tid >> 5;
    const f32x4 zf4 = {0.f, 0.f, 0.f, 0.f};

    stage(0, 0);
    __syncthreads();
    for (int kt = 0; kt < KT_; kt++) {
        int cur = kt & 1;
        if (kt + 1 < KT_) stage(cur ^ 1, kt + 1);
        if (kt < 8)
            __builtin_nontemporal_store(zf4, (f32x4*)(Fb + (size_t)(zr0 + kt * 16) * S_ + zc4));
        bf16x8 ah[4], bh[2];
#pragma unroll
        for (int i = 0; i < 4; i++) {
            int offA = (wr * 4 + i) * 1024 + lane * 16;
            ah[i] = *(const bf16x8*)&lds[cur][0][offA];
        }
#pragma unroll
        for (int j = 0; j < 2; j++) {
            int offB = (wc * 2 + j) * 1024 + lane * 16;
            bh[j] = *(const bf16x8*)&lds[cur][1][offB];
        }
#pragma unroll
        for (int i = 0; i < 4; i++)
#pragma unroll
            for (int j = 0; j < 2; j++)
                acc[i][j] = __builtin_amdgcn_mfma_f32_16x16x32_bf16(ah[i], bh[j], acc[i][j], 0, 0, 0);
        __syncthreads();
    }

    const int col0 = nb * 128 + wc * 32 + (lane & 15);
    const int row0 = mb * 128 + wr * 64 + (lane >> 4) * 4;
    float b1v[2];
    int dd[2];
#pragma unroll
    for (int j = 0; j < 2; j++) {
        b1v[j] = b1[col0 + j * 16];
        dd[j] = (deadf[col0 + j * 16] >= DEAD_THRESH) ? 1 : 0;
    }
    const uint32_t gseg = (uint32_t)(mb * 128 + nb) * 8 + w;
    uint2* segM = glM + (size_t)gseg * CAPSEG_M;
    uint2* segD = glD + (size_t)gseg * CAPSEG_D;
    const uint64_t lmlt = ((uint64_t)1 << lane) - 1;
    uint32_t runM = 0, runD = 0;
#pragma unroll
    for (int i = 0; i < 4; i++)
#pragma unroll
        for (int j = 0; j < 2; j++)
#pragma unroll
            for (int r = 0; r < 4; r++) {
                float v = fmaxf(acc[i][j][r] + b1v[j], 0.0f);
                bool pass = v >= T_LO;
                uint64_t mask = __ballot(pass);
                if (mask) {
                    uint32_t prefix = (uint32_t)__popcll(mask & lmlt);
                    uint2 ent;
                    ent.x = (uint32_t)(row0 + i * 16 + r) * S_ + (uint32_t)(col0 + j * 16);
                    ent.y = __float_as_uint(v);
                    if (pass && runM + prefix < CAPSEG_M) segM[runM + prefix] = ent;
                    runM += (uint32_t)__popcll(mask);
                    bool dp = pass && dd[j];
                    uint64_t dmask = __ballot(dp);
                    if (dmask) {
                        uint32_t dprefix = (uint32_t)__popcll(dmask & lmlt);
                        if (dp && runD + dprefix < CAPSEG_D) segD[runD + dprefix] = ent;
                        runD += (uint32_t)__popcll(dmask);
                    }
                }
            }
    if (lane == 0) {
        bcM[gseg] = runM < CAPSEG_M ? runM : CAPSEG_M;
        bcD[gseg] = runD < CAPSEG_D ? runD : CAPSEG_D;
    }
}

// -------- parallel exclusive prefix over 32768 segment counts (1024 thr, uint4) ------
__global__ __launch_bounds__(1024) void seg_scan_k(const uint32_t* __restrict__ bcM,
                                                   const uint32_t* __restrict__ bcD,
                                                   uint32_t* __restrict__ soM,
                                                   uint32_t* __restrict__ soD,
                                                   uint32_t* __restrict__ cnts) {
    __shared__ uint32_t part[1024];
    const int t = threadIdx.x;
    for (int sel = 0; sel < 2; sel++) {
        const uint32_t* bc = sel ? bcD : bcM;
        uint32_t* so = sel ? soD : soM;
        const uint4* b4 = (const uint4*)(bc + t * 32);
        uint32_t s = 0;
#pragma unroll
        for (int i = 0; i < 8; i++) {
            uint4 v = b4[i];
            s += v.x + v.y + v.z + v.w;
        }
        part[t] = s;
        __syncthreads();
        for (int d = 1; d < 1024; d <<= 1) {
            uint32_t v = (t >= d) ? part[t - d] : 0;
            __syncthreads();
            part[t] += v;
            __syncthreads();
        }
        uint32_t run = (t == 0) ? 0 : part[t - 1];
        uint4* so4 = (uint4*)(so + t * 32);
#pragma unroll
        for (int i = 0; i < 8; i++) {
            uint4 v = b4[i];
            uint4 o;
            o.x = run; run += v.x;
            o.y = run; run += v.y;
            o.z = run; run += v.z;
            o.w = run; run += v.w;
            so4[i] = o;
        }
        if (t == 1023) cnts[sel] = run;
        __syncthreads();
    }
}

// ---------------- compact segments to dense lists + histogram, y=0 M / y=1 D ------
__global__ __launch_bounds__(256) void compact_hist_k(const uint2* __restrict__ glM,
                                                      const uint2* __restrict__ glD,
                                                      const uint32_t* __restrict__ bcM,
                                                      const uint32_t* __restrict__ bcD,
                                                      const uint32_t* __restrict__ soM,
                                                      const uint32_t* __restrict__ soD,
                                                      uint2* __restrict__ cmpM,
                                                      uint2* __restrict__ cmpD,
                                                      uint32_t* __restrict__ ghM,
                                                      uint32_t* __restrict__ ghD) {
    __shared__ uint32_t h[NBIN];
    int sel = blockIdx.y;
    const uint2* list = sel ? glD : glM;
    const uint32_t* bc = sel ? bcD : bcM;
    const uint32_t* so = sel ? soD : soM;
    uint2* cmp = sel ? cmpD : cmpM;
    uint32_t cap = sel ? CAPSEG_D : CAPSEG_M;
    uint32_t* gh = sel ? ghD : ghM;
    for (int i = threadIdx.x; i < NBIN; i += 256) h[i] = 0;
    __syncthreads();
    const int wv = threadIdx.x >> 6, lane = threadIdx.x & 63;
    for (uint32_t seg = blockIdx.x * 4 + wv; seg < NSEG; seg += gridDim.x * 4) {
        uint32_t n = bc[seg], off = so[seg];
        for (uint32_t i = lane; i < n; i += 64) {
            uint2 e = list[(size_t)seg * cap + i];
            cmp[off + i] = e;
            atomicAdd(&h[binOf(__uint_as_float(e.y))], 1u);
        }
    }
    __syncthreads();
    for (int i = threadIdx.x; i < NBIN; i += 256)
        if (h[i]) atomicAdd(&gh[i], h[i]);
}

// ---------------- find boundary bin b* (parallel chunked scan) ----------------
__global__ __launch_bounds__(256) void scan_k(const uint32_t* __restrict__ ghM,
                                              const uint32_t* __restrict__ ghD,
                                              uint32_t* __restrict__ scal) {
    __shared__ uint32_t h[NBIN];
    __shared__ uint32_t csum[64];
    for (int sel = 0; sel < 2; sel++) {
        const uint32_t* gh = sel ? ghD : ghM;
        uint32_t need = sel ? NEED_DEAD : NEED_MAIN;
        for (int i = threadIdx.x; i < NBIN; i += 256) h[i] = gh[i];
        __syncthreads();
        if (threadIdx.x < 64) {
            uint32_t s = 0;
#pragma unroll
            for (int j = 0; j < 32; j++) s += h[threadIdx.x * 32 + j];
            csum[threadIdx.x] = s;
        }
        __syncthreads();
        if (threadIdx.x == 0) {
            uint32_t cum = 0; int c = 63;
            for (; c > 0; c--) { uint32_t cc = csum[c]; if (cum + cc >= need) break; cum += cc; }
            int b = c * 32 + 31;
            for (; b > c * 32; b--) { uint32_t cc = h[b]; if (cum + cc >= need) break; cum += cc; }
            uint32_t extra = 0;
            for (int j = b + 1; j < b + REG_W && j < NBIN; j++) extra += h[j];
            scal[sel ? 2 : 0] = (uint32_t)b;
            scal[sel ? 3 : 1] = need - cum + extra;
        }
        __syncthreads();
    }
}

// ------- pull boundary-region (bins b*-REG_W .. b*+REG_W-1) from dense lists --------
__global__ __launch_bounds__(256) void bnd_filter_k(const uint2* __restrict__ cmpM,
                                                    const uint2* __restrict__ cmpD,
                                                    const uint32_t* __restrict__ scal,
                                                    uint2* __restrict__ bndM,
                                                    uint2* __restrict__ bndD,
                                                    uint32_t* __restrict__ cnts) {
    int sel = blockIdx.y;
    const uint2* list = sel ? cmpD : cmpM;
    uint2* bnd = sel ? bndD : bndM;
    uint32_t n = cnts[sel];
    uint32_t bs = scal[sel ? 2 : 0];
    for (uint32_t i = blockIdx.x * 256 + threadIdx.x; i < n; i += gridDim.x * 256) {
        uint2 ent = list[i];
        uint32_t bb = binOf(__uint_as_float(ent.y));
        if (bb + REG_W >= bs && bb <= bs + REG_W - 1) {
            uint32_t p = atomicAdd(&cnts[2 + sel], 1u);
            if (p < BNDCAP) bnd[p] = ent;
        }
    }
}

// ---------------- fp64 recompute, wave-per-candidate (4 per block) ----------------
__global__ __launch_bounds__(256) void bnd_f64_k(const uint2* __restrict__ bndM,
                                                 const uint2* __restrict__ bndD,
                                                 const uint32_t* __restrict__ cnts,
                                                 const float* __restrict__ x,
                                                 const float* __restrict__ w1,
                                                 const float* __restrict__ b1,
                                                 const float* __restrict__ b2,
                                                 double* __restrict__ bvM,
                                                 double* __restrict__ bvD) {
    int sel = blockIdx.y;
    const uint2* bnd = sel ? bndD : bndM;
    double* bv64 = sel ? bvD : bvM;
    uint32_t n = cnts[2 + sel]; if (n > BNDCAP) n = BNDCAP;
    uint32_t i = blockIdx.x * 4 + (threadIdx.x >> 6);
    if (i >= n) return;
    const int lane = threadIdx.x & 63;
    uint2 ent = bnd[i];
    uint32_t m = ent.x >> 14, s = ent.x & (S_ - 1);
    const float* xr = x + (size_t)m * H_;
    const float* wr = w1 + (size_t)s * H_;
    double sum = 0.0;
#pragma unroll
    for (int e = 0; e < 8; e++) {
        int k = lane + e * 64;
        sum += ((double)xr[k] - (double)b2[k]) * (double)wr[k];
    }
#pragma unroll
    for (int off = 32; off; off >>= 1) sum += __shfl_down(sum, off, 64);
    if (lane == 0) {
        double tot = sum + (double)b1[s];
        bv64[i] = tot > 0.0 ? tot : 0.0;
    }
}

// ------ exact top-r' in region: O(n) histogram-select + tie rank; DIRECT writes ------
__global__ __launch_bounds__(1024) void rank_hist_k(const uint2* __restrict__ bndM,
                                                    const double* __restrict__ bvM,
                                                    const uint2* __restrict__ bndD,
                                                    const double* __restrict__ bvD,
                                                    uint32_t* __restrict__ cnts,
                                                    const uint32_t* __restrict__ scal,
                                                    float* __restrict__ fsp,
                                                    uint2* __restrict__ entM,
                                                    uint2* __restrict__ entD,
                                                    uint32_t* __restrict__ rcM,
                                                    uint32_t* __restrict__ rcD) {
    int sel = blockIdx.x;
    const uint2* bnd = sel ? bndD : bndM;
    const double* bv = sel ? bvD : bvM;
    uint2* entries = sel ? entD : entM;
    uint32_t* rowCnt = sel ? rcD : rcM;
    const int capRow = sel ? CAPROW_D : CAPROW_M;
    uint32_t n = cnts[2 + sel]; if (n > BNDCAP) n = BNDCAP;
    uint32_t r = scal[sel ? 3 : 1]; if (r > n) r = n;
    uint32_t bs = scal[sel ? 2 : 0];
    uint32_t loBin = bs - (REG_W + PAD_BINS);
    uint32_t hiBin = bs + (REG_W + PAD_BINS);
    double lo = (double)__uint_as_float(BIN_BASE + (loBin << BIN_SHIFT));
    double hi = (double)__uint_as_float(BIN_BASE + (hiBin << BIN_SHIFT));
    double scale = (double)NSUB / (hi - lo);

    __shared__ uint32_t h[NSUB];
    __shared__ uint32_t cs[1024];
    __shared__ uint32_t c2[64];
    __shared__ uint32_t sCb, sAbove, sTieCnt;
    __shared__ double tieV[TIECAP];
    __shared__ uint2 tieE[TIECAP];
    const int t = threadIdx.x;
    for (int i = t; i < NSUB; i += 1024) h[i] = 0;
    if (t == 0) sTieCnt = 0;
    __syncthreads();
    for (uint32_t i = t; i < n; i += 1024) {
        double v = bv[i];
        int k = (int)((v - lo) * scale);
        k = k < 0 ? 0 : (k > NSUB - 1 ? NSUB - 1 : k);
        atomicAdd(&h[k], 1u);
    }
    __syncthreads();
    {
        uint32_t s = 0;
#pragma unroll
        for (int j = 0; j < 8; j++) s += h[t * 8 + j];
        cs[t] = s;
    }
    __syncthreads();
    if (t < 64) {
        uint32_t s = 0;
#pragma unroll
        for (int j = 0; j < 16; j++) s += cs[t * 16 + j];
        c2[t] = s;
    }
    __syncthreads();
    if (t == 0) {
        uint32_t cum = 0; int w2 = 63;
        for (; w2 > 0; w2--) { if (cum + c2[w2] >= r) break; cum += c2[w2]; }
        int c = w2 * 16 + 15;
        for (; c > w2 * 16; c--) { if (cum + cs[c] >= r) break; cum += cs[c]; }
        int b = c * 8 + 7;
        for (; b > c * 8; b--) { if (cum + h[b] >= r) break; cum += h[b]; }
        sCb = (uint32_t)b;
        sAbove = cum;
    }
    __syncthreads();
    const uint32_t cb = sCb;
    uint32_t rr = r - sAbove;
    const int lane = t & 63;
    const uint64_t lmlt = ((uint64_t)1 << lane) - 1;
    for (uint32_t i0 = 0; i0 < n; i0 += 1024) {
        uint32_t i = i0 + t;
        bool valid = i < n;
        double v = valid ? bv[i] : -1.0;
        uint32_t k = 0;
        if (valid) {
            int kk = (int)((v - lo) * scale);
            k = (uint32_t)(kk < 0 ? 0 : (kk > NSUB - 1 ? NSUB - 1 : kk));
        }
        if (valid && k > cb) {
            uint2 ent = bnd[i];
            float fv = __uint_as_float(ent.y);
            if (!sel) fsp[ent.x] = fv;
            uint32_t row = ent.x >> 14;
            uint32_t slot = atomicAdd(&rowCnt[row], 1u);
            if (slot < (uint32_t)capRow)
                entries[(size_t)row * capRow + slot] = make_uint2(ent.x & (S_ - 1), ent.y);
        }
        bool tie = valid && k == cb;
        uint64_t tm = __ballot(tie);
        if (tm) {
            uint32_t base = 0;
            if (lane == 0) base = atomicAdd(&sTieCnt, (uint32_t)__popcll(tm));
            base = __shfl(base, 0, 64);
            if (tie) {
                uint32_t p = base + __popcll(tm & lmlt);
                if (p < TIECAP) { tieV[p] = v; tieE[p] = bnd[i]; }
            }
        }
    }
    __syncthreads();
    uint32_t tc = sTieCnt; if (tc > TIECAP) tc = TIECAP;
    if (rr > tc) rr = tc;
    if (t < (int)tc) {
        double vi = tieV[t]; uint32_t ii = tieE[t].x;
        uint32_t rank = 0;
        for (uint32_t j = 0; j < tc; j++) {
            double vj = tieV[j]; uint32_t ij = tieE[j].x;
            rank += (vj > vi || (vj == vi && ij < ii)) ? 1u : 0u;
        }
        if (rank < rr) {
            uint2 ent = tieE[t];
            float fv = __uint_as_float(ent.y);
            if (!sel) fsp[ent.x] = fv;
            uint32_t row = ent.x >> 14;
            uint32_t slot = atomicAdd(&rowCnt[row], 1u);
            if (slot < (uint32_t)capRow)
                entries[(size_t)row * capRow + slot] = make_uint2(ent.x & (S_ - 1), ent.y);
        }
    }
}

// ---------------- scatter uncond picks (bins >= b*+REG_W) from dense lists ----------
__global__ __launch_bounds__(256) void scatter_list_k(const uint2* __restrict__ cmpM,
                                                      const uint2* __restrict__ cmpD,
                                                      const uint32_t* __restrict__ cnts,
                                                      const uint32_t* __restrict__ scal,
                                                      float* __restrict__ fsp,
                                                      uint2* __restrict__ entM,
                                                      uint2* __restrict__ entD,
                                                      uint32_t* __restrict__ rcM,
                                                      uint32_t* __restrict__ rcD) {
    int sel = blockIdx.y;
    const uint2* list = sel ? cmpD : cmpM;
    uint2* entries = sel ? entD : entM;
    uint32_t* rowCnt = sel ? rcD : rcM;
    int capRow = sel ? CAPROW_D : CAPROW_M;
    uint32_t n = cnts[sel];
    uint32_t bsReg = scal[sel ? 2 : 0] + REG_W - 1;
    for (uint32_t i = blockIdx.x * 256 + threadIdx.x; i < n; i += gridDim.x * 256) {
        uint2 ent = list[i];
        float v = __uint_as_float(ent.y);
        if (binOf(v) <= bsReg) continue;   // region handled by rank_hist_k
        if (!sel) fsp[ent.x] = v;
        uint32_t row = ent.x >> 14;
        uint32_t slot = atomicAdd(&rowCnt[row], 1u);
        if (slot < (uint32_t)capRow)
            entries[(size_t)row * capRow + slot] = make_uint2(ent.x & (S_ - 1), ent.y);
    }
}

// ---------------- sparse decode: x_rec & dead_x (bf16 W2T) ----------------
__global__ __launch_bounds__(512) void decode_k(const uint2* __restrict__ entM,
                                                const uint32_t* __restrict__ rcM,
                                                const uint2* __restrict__ entD,
                                                const uint32_t* __restrict__ rcD,
                                                const uint16_t* __restrict__ W2T,
                                                const float* __restrict__ b2,
                                                float* __restrict__ xrec,
                                                float* __restrict__ deadx) {
    __shared__ uint2 em[CAPROW_M];
    __shared__ uint2 ed[CAPROW_D];
    int b = blockIdx.x, h = threadIdx.x;
    uint32_t nm = rcM[b]; if (nm > CAPROW_M) nm = CAPROW_M;
    uint32_t nd = rcD[b]; if (nd > CAPROW_D) nd = CAPROW_D;
    for (uint32_t i = h; i < nm; i += 512) em[i] = entM[(size_t)b * CAPROW_M + i];
    for (uint32_t i = h; i < nd; i += 512) ed[i] = entD[(size_t)b * CAPROW_D + i];
    __syncthreads();
    float bias = b2[h];
    float a = bias, d = bias;
    for (uint32_t i = 0; i < nm; i++)
        a = fmaf(__uint_as_float(em[i].y), bf2f(W2T[(size_t)em[i].x * H_ + h]), a);
    for (uint32_t i = 0; i < nd; i++)
        d = fmaf(__uint_as_float(ed[i].y), bf2f(W2T[(size_t)ed[i].x * H_ + h]), d);
    xrec[(size_t)b * H_ + h] = a;
    deadx[(size_t)b * H_ + h] = d;
}

extern "C" void kernel_launch(void* const* d_in, const int* in_sizes, int n_in,
                              void* d_out, int out_size, void* d_ws, size_t ws_size,
                              hipStream_t stream) {
    const float* x = (const float*)d_in[0];
    const float* w1 = (const float*)d_in[1];
    const float* b1 = (const float*)d_in[2];
    const float* w2 = (const float*)d_in[3];
    const float* b2 = (const float*)d_in[4];
    const int* deadf = (const int*)d_in[5];

    float* out = (float*)d_out;
    float* xrec = out;
    float* fsp = out + (size_t)B_ * H_;
    float* deadx = out + (size_t)B_ * H_ + (size_t)B_ * S_;

    uint8_t* w = (uint8_t*)d_ws;
    size_t off = 0;
    auto alloc = [&](size_t bytes) { uint8_t* p = w + off; off = (off + bytes + 255) & ~(size_t)255; return p; };

    uint16_t* W2T = (uint16_t*)alloc((size_t)S_ * H_ * 2);
    uint8_t* ctrl = alloc(NBIN * 8 + 128 + (size_t)B_ * 8);
    uint32_t* ghM = (uint32_t*)ctrl;
    uint32_t* ghD = (uint32_t*)(ctrl + NBIN * 4);
    uint32_t* cnts = (uint32_t*)(ctrl + NBIN * 8);         // [0]totM [1]totD [2]bndM [3]bndD
    uint32_t* scal = (uint32_t*)(ctrl + NBIN * 8 + 64);    // [0]bstarM [1]rM [2]bstarD [3]rD
    uint32_t* rcM = (uint32_t*)(ctrl + NBIN * 8 + 128);
    uint32_t* rcD = (uint32_t*)(ctrl + NBIN * 8 + 128 + B_ * 4);
    size_t ctrlBytes = NBIN * 8 + 128 + (size_t)B_ * 8;

    uint2* listM = (uint2*)alloc((size_t)NSEG * CAPSEG_M * 8);
    uint2* listD = (uint2*)alloc((size_t)NSEG * CAPSEG_D * 8);
    uint32_t* bcM = (uint32_t*)alloc((size_t)NSEG * 4);
    uint32_t* bcD = (uint32_t*)alloc((size_t)NSEG * 4);
    uint32_t* soM = (uint32_t*)alloc((size_t)NSEG * 4);
    uint32_t* soD = (uint32_t*)alloc((size_t)NSEG * 4);
    uint2* cmpM = (uint2*)alloc((size_t)NSEG * CAPSEG_M * 8);
    uint2* cmpD = (uint2*)alloc((size_t)NSEG * CAPSEG_D * 8);
    uint2* bndM = (uint2*)alloc((size_t)BNDCAP * 8);
    uint2* bndD = (uint2*)alloc((size_t)BNDCAP * 8);
    double* bvM = (double*)alloc((size_t)BNDCAP * 8);
    double* bvD = (double*)alloc((size_t)BNDCAP * 8);
    uint2* entM = (uint2*)alloc((size_t)B_ * CAPROW_M * 8);
    uint2* entD = (uint2*)alloc((size_t)B_ * CAPROW_D * 8);
    uint8_t* AhT = alloc((size_t)B_ * H_ * 2);
    uint8_t* WhT = alloc((size_t)S_ * H_ * 2);

    (void)hipMemsetAsync(ctrl, 0, ctrlBytes, stream);
    prep_k<<<13312, 256, 0, stream>>>(w2, W2T, x, w1, b2, AhT, WhT);
    gemm_fused<<<dim3(512, 8), 512, 0, stream>>>(AhT, WhT, b1, deadf,
                                                 listM, listD, bcM, bcD, fsp);
    seg_scan_k<<<1, 1024, 0, stream>>>(bcM, bcD, soM, soD, cnts);
    compact_hist_k<<<dim3(1024, 2), 256, 0, stream>>>(listM, listD, bcM, bcD, soM, soD,
                                                      cmpM, cmpD, ghM, ghD);
    scan_k<<<1, 256, 0, stream>>>(ghM, ghD, scal);
    bnd_filter_k<<<dim3(1024, 2), 256, 0, stream>>>(cmpM, cmpD, scal, bndM, bndD, cnts);
    bnd_f64_k<<<dim3(BNDCAP / 4, 2), 256, 0, stream>>>(bndM, bndD, cnts, x, w1, b1, b2, bvM, bvD);
    rank_hist_k<<<2, 1024, 0, stream>>>(bndM, bvM, bndD, bvD, cnts, scal,
                                        fsp, entM, entD, rcM, rcD);
    scatter_list_k<<<dim3(1024, 2), 256, 0, stream>>>(cmpM, cmpD, cnts, scal, fsp,
                                                      entM, entD, rcM, rcD);
    decode_k<<<B_, 512, 0, stream>>>(entM, rcM, entD, rcD, W2T, b2, xrec, deadx);
}

// Round 16
// 414.254 us; speedup vs baseline: 1.5324x; 1.0236x over previous
//
#include <hip/hip_runtime.h>
#include <stdint.h>

#define B_  4096
#define H_  512
#define S_  16384
#define KT_ 16            // H_/32 K-steps of 32
#define NEED_MAIN 131072  // K*B
#define NEED_DEAD 65536   // DEAD_K*B
#define DEAD_THRESH 5

#define T_LO 1.05078125f         // exact bin edge: 0x3F868000
#define BIN_BASE 0x3F800000u
#define BIN_SHIFT 13
#define NBIN 2048                // covers [1.0, 4.0)
#define REG_W 8                  // f64-rescue region = [b*-8, b*+7]; uncond >= b*+8
#define PAD_BINS 8               // 1-term gemm: f64 drift up to ~5 bins
#define NSUB 8192
#define TIECAP 512

#define NSEG 32768               // 4096 blocks x 8 waves
#define CAPSEG_M 128             // lambda ~21
#define CAPSEG_D 64              // lambda ~10
#define BNDCAP 16384
#define CAPROW_M 192
#define CAPROW_D 128

#define CTRL_BYTES (NBIN * 8 + 128 + B_ * 8)
#define CTRL_U4 ((CTRL_BYTES + 15) / 16)
#define ZBLK ((CTRL_U4 + 255) / 256)     // 13 blocks zero the ctrl region

typedef __bf16 bf16x8 __attribute__((ext_vector_type(8)));
typedef float f32x4 __attribute__((ext_vector_type(4)));
typedef unsigned short ushort8 __attribute__((ext_vector_type(8)));
typedef unsigned int uint4v __attribute__((ext_vector_type(4)));

__device__ __forceinline__ uint32_t binOf(float v) {
    uint32_t b = (__float_as_uint(v) - BIN_BASE) >> BIN_SHIFT;
    return b > (NBIN - 1) ? (NBIN - 1) : b;
}
__device__ __forceinline__ uint16_t f2bf(float f) {
    uint32_t u = __float_as_uint(f);
    uint32_t r = u + 0x7FFFu + ((u >> 16) & 1u);   // RNE
    return (uint16_t)(r >> 16);
}
__device__ __forceinline__ float bf2f(uint16_t b) {
    return __uint_as_float((uint32_t)b << 16);
}
__device__ __forceinline__ void gload16(const void* g, void* l) {
    __builtin_amdgcn_global_load_lds((const __attribute__((address_space(1))) uint32_t*)g,
                                     (__attribute__((address_space(3))) uint32_t*)l, 16, 0, 0);
}

// ------ fused prep: blocks 0..8191 transpose W2->bf16 W2T; 8192..13311 split x/w1;
//        blocks 13312.. zero the ctrl region (replaces hipMemsetAsync) -------------
__global__ __launch_bounds__(256) void prep_k(const float* __restrict__ W2,
                                              uint16_t* __restrict__ W2T,
                                              const float* __restrict__ x,
                                              const float* __restrict__ w1,
                                              const float* __restrict__ b2,
                                              uint8_t* __restrict__ AhT,
                                              uint8_t* __restrict__ WhT,
                                              uint8_t* __restrict__ ctrl) {
    __shared__ float tile[32][33];
    int b = blockIdx.x;
    if (b >= 13312) {
        uint32_t i = (uint32_t)(b - 13312) * 256 + threadIdx.x;
        if (i < CTRL_U4) {
            uint4v z = {0u, 0u, 0u, 0u};
            *(uint4v*)(ctrl + (size_t)i * 16) = z;
        }
        return;
    }
    if (b < 8192) {
        int s0 = (b & 511) * 32, h0 = (b >> 9) * 32;
        int tx = threadIdx.x & 31, ty = threadIdx.x >> 5;
#pragma unroll
        for (int i = 0; i < 4; i++) {
            int h = h0 + ty + i * 8;
            tile[ty + i * 8][tx] = W2[(size_t)h * S_ + s0 + tx];
        }
        __syncthreads();
#pragma unroll
        for (int i = 0; i < 4; i++) {
            int s = s0 + ty + i * 8;
            W2T[(size_t)s * H_ + h0 + tx] = f2bf(tile[tx][ty + i * 8]);
        }
        return;
    }
    int bb = b - 8192;
    int isX = bb < 1024;
    int tid = (isX ? bb : bb - 1024) * 256 + threadIdx.x;
    int r = tid >> 6, h8 = tid & 63;
    int k0 = h8 << 3;
    const float* src = isX ? x : w1;
    const float* s = src + (size_t)r * H_ + k0;
    float4 v0 = *(const float4*)s, v1 = *(const float4*)(s + 4);
    float a[8] = {v0.x, v0.y, v0.z, v0.w, v1.x, v1.y, v1.z, v1.w};
    if (isX) {
        float4 c0 = *(const float4*)(b2 + k0), c1 = *(const float4*)(b2 + k0 + 4);
        a[0] -= c0.x; a[1] -= c0.y; a[2] -= c0.z; a[3] -= c0.w;
        a[4] -= c1.x; a[5] -= c1.y; a[6] -= c1.z; a[7] -= c1.w;
    }
    ushort8 Hh;
#pragma unroll
    for (int e = 0; e < 8; e++) Hh[e] = f2bf(a[e]);
    int rb = r >> 7, kt = k0 >> 5;
    int mf = (r >> 4) & 7;
    int ln = (r & 15) | (((k0 >> 3) & 3) << 4);
    size_t byte = ((size_t)rb * KT_ + kt) * 8192 + (size_t)mf * 1024 + (size_t)ln * 16;
    if (isX) *(ushort8*)(AhT + byte) = Hh;
    else     *(ushort8*)(WhT + byte) = Hh;
}

// ------- f = relu((x-b2)@W1^T + b1) via 1x bf16 MFMA, 8 waves of 64x32, collect ------
// 32KB LDS; launch_bounds(512,8) caps 64 VGPR -> 4 blocks/CU (full occupancy).
__global__ __launch_bounds__(512, 8) void gemm_fused(const uint8_t* __restrict__ AhT,
                                                     const uint8_t* __restrict__ WhT,
                                                     const float* __restrict__ b1,
                                                     const int* __restrict__ deadf,
                                                     uint2* __restrict__ glM,
                                                     uint2* __restrict__ glD,
                                                     uint32_t* __restrict__ bcM,
                                                     uint32_t* __restrict__ bcD,
                                                     float* __restrict__ fsp) {
    __shared__ uint8_t lds[2][2][8192];   // [buf][Ah,Wh][tile]
    const int tid = threadIdx.x;
    const int lane = tid & 63, w = tid >> 6;     // 8 waves
    const int wr = w >> 2, wc = w & 3;           // wave tile 64x32
    const int lin = blockIdx.y * 512 + blockIdx.x;
    const int xcd = lin & 7, idx = lin >> 3;
    const int mb = xcd * 4 + (idx & 3), nb = idx >> 2;   // mb-fastest within XCD

    const uint8_t* gAh = AhT + (size_t)mb * KT_ * 8192;
    const uint8_t* gBh = WhT + (size_t)nb * KT_ * 8192;

    f32x4 acc[4][2];
#pragma unroll
    for (int i = 0; i < 4; i++)
#pragma unroll
        for (int j = 0; j < 2; j++) acc[i][j] = (f32x4){0.f, 0.f, 0.f, 0.f};

    auto stage = [&](int buf, int kt) {
        size_t tb = (size_t)kt * 8192;
        int o = tid * 16;
        gload16(gAh + tb + o, &lds[buf][0][o]);
        gload16(gBh + tb + o, &lds[buf][1][o]);
    };

    float* Fb = fsp + (size_t)(mb * 128) * S_ + nb * 128;
    const int zc4 = (tid & 31) * 4, zr0 = tid >> 5;
    const f32x4 zf4 = {0.f, 0.f, 0.f, 0.f};

    stage(0, 0);
    __syncthreads();
    for (int kt = 0; kt < KT_; kt++) {
        int cur = kt & 1;
        if (kt + 1 < KT_) stage(cur ^ 1, kt + 1);
        if (kt < 8)
            __builtin_nontemporal_store(zf4, (f32x4*)(Fb + (size_t)(zr0 + kt * 16) * S_ + zc4));
        bf16x8 ah[4], bh[2];
#pragma unroll
        for (int i = 0; i < 4; i++) {
            int offA = (wr * 4 + i) * 1024 + lane * 16;
            ah[i] = *(const bf16x8*)&lds[cur][0][offA];
        }
#pragma unroll
        for (int j = 0; j < 2; j++) {
            int offB = (wc * 2 + j) * 1024 + lane * 16;
            bh[j] = *(const bf16x8*)&lds[cur][1][offB];
        }
#pragma unroll
        for (int i = 0; i < 4; i++)
#pragma unroll
            for (int j = 0; j < 2; j++)
                acc[i][j] = __builtin_amdgcn_mfma_f32_16x16x32_bf16(ah[i], bh[j], acc[i][j], 0, 0, 0);
        __syncthreads();
    }

    const int col0 = nb * 128 + wc * 32 + (lane & 15);
    const int row0 = mb * 128 + wr * 64 + (lane >> 4) * 4;
    float b1v[2];
    int dd[2];
#pragma unroll
    for (int j = 0; j < 2; j++) {
        b1v[j] = b1[col0 + j * 16];
        dd[j] = (deadf[col0 + j * 16] >= DEAD_THRESH) ? 1 : 0;
    }
    const uint32_t gseg = (uint32_t)(mb * 128 + nb) * 8 + w;
    uint2* segM = glM + (size_t)gseg * CAPSEG_M;
    uint2* segD = glD + (size_t)gseg * CAPSEG_D;
    const uint64_t lmlt = ((uint64_t)1 << lane) - 1;
    uint32_t runM = 0, runD = 0;
#pragma unroll
    for (int i = 0; i < 4; i++)
#pragma unroll
        for (int j = 0; j < 2; j++)
#pragma unroll
            for (int r = 0; r < 4; r++) {
                float v = fmaxf(acc[i][j][r] + b1v[j], 0.0f);
                bool pass = v >= T_LO;
                uint64_t mask = __ballot(pass);
                if (mask) {
                    uint32_t prefix = (uint32_t)__popcll(mask & lmlt);
                    uint2 ent;
                    ent.x = (uint32_t)(row0 + i * 16 + r) * S_ + (uint32_t)(col0 + j * 16);
                    ent.y = __float_as_uint(v);
                    if (pass && runM + prefix < CAPSEG_M) segM[runM + prefix] = ent;
                    runM += (uint32_t)__popcll(mask);
                    bool dp = pass && dd[j];
                    uint64_t dmask = __ballot(dp);
                    if (dmask) {
                        uint32_t dprefix = (uint32_t)__popcll(dmask & lmlt);
                        if (dp && runD + dprefix < CAPSEG_D) segD[runD + dprefix] = ent;
                        runD += (uint32_t)__popcll(dmask);
                    }
                }
            }
    if (lane == 0) {
        bcM[gseg] = runM < CAPSEG_M ? runM : CAPSEG_M;
        bcD[gseg] = runD < CAPSEG_D ? runD : CAPSEG_D;
    }
}

// -------- parallel exclusive prefix over 32768 segment counts (1024 thr, uint4) ------
__global__ __launch_bounds__(1024) void seg_scan_k(const uint32_t* __restrict__ bcM,
                                                   const uint32_t* __restrict__ bcD,
                                                   uint32_t* __restrict__ soM,
                                                   uint32_t* __restrict__ soD,
                                                   uint32_t* __restrict__ cnts) {
    __shared__ uint32_t part[1024];
    const int t = threadIdx.x;
    for (int sel = 0; sel < 2; sel++) {
        const uint32_t* bc = sel ? bcD : bcM;
        uint32_t* so = sel ? soD : soM;
        const uint4* b4 = (const uint4*)(bc + t * 32);
        uint32_t s = 0;
#pragma unroll
        for (int i = 0; i < 8; i++) {
            uint4 v = b4[i];
            s += v.x + v.y + v.z + v.w;
        }
        part[t] = s;
        __syncthreads();
        for (int d = 1; d < 1024; d <<= 1) {
            uint32_t v = (t >= d) ? part[t - d] : 0;
            __syncthreads();
            part[t] += v;
            __syncthreads();
        }
        uint32_t run = (t == 0) ? 0 : part[t - 1];
        uint4* so4 = (uint4*)(so + t * 32);
#pragma unroll
        for (int i = 0; i < 8; i++) {
            uint4 v = b4[i];
            uint4 o;
            o.x = run; run += v.x;
            o.y = run; run += v.y;
            o.z = run; run += v.z;
            o.w = run; run += v.w;
            so4[i] = o;
        }
        if (t == 1023) cnts[sel] = run;
        __syncthreads();
    }
}

// ---------------- compact segments to dense lists + histogram, y=0 M / y=1 D ------
__global__ __launch_bounds__(256) void compact_hist_k(const uint2* __restrict__ glM,
                                                      const uint2* __restrict__ glD,
                                                      const uint32_t* __restrict__ bcM,
                                                      const uint32_t* __restrict__ bcD,
                                                      const uint32_t* __restrict__ soM,
                                                      const uint32_t* __restrict__ soD,
                                                      uint2* __restrict__ cmpM,
                                                      uint2* __restrict__ cmpD,
                                                      uint32_t* __restrict__ ghM,
                                                      uint32_t* __restrict__ ghD) {
    __shared__ uint32_t h[NBIN];
    int sel = blockIdx.y;
    const uint2* list = sel ? glD : glM;
    const uint32_t* bc = sel ? bcD : bcM;
    const uint32_t* so = sel ? soD : soM;
    uint2* cmp = sel ? cmpD : cmpM;
    uint32_t cap = sel ? CAPSEG_D : CAPSEG_M;
    uint32_t* gh = sel ? ghD : ghM;
    for (int i = threadIdx.x; i < NBIN; i += 256) h[i] = 0;
    __syncthreads();
    const int wv = threadIdx.x >> 6, lane = threadIdx.x & 63;
    for (uint32_t seg = blockIdx.x * 4 + wv; seg < NSEG; seg += gridDim.x * 4) {
        uint32_t n = bc[seg], off = so[seg];
        for (uint32_t i = lane; i < n; i += 64) {
            uint2 e = list[(size_t)seg * cap + i];
            cmp[off + i] = e;
            atomicAdd(&h[binOf(__uint_as_float(e.y))], 1u);
        }
    }
    __syncthreads();
    for (int i = threadIdx.x; i < NBIN; i += 256)
        if (h[i]) atomicAdd(&gh[i], h[i]);
}

// ---------------- find boundary bin b* (parallel chunked scan) ----------------
__global__ __launch_bounds__(256) void scan_k(const uint32_t* __restrict__ ghM,
                                              const uint32_t* __restrict__ ghD,
                                              uint32_t* __restrict__ scal) {
    __shared__ uint32_t h[NBIN];
    __shared__ uint32_t csum[64];
    for (int sel = 0; sel < 2; sel++) {
        const uint32_t* gh = sel ? ghD : ghM;
        uint32_t need = sel ? NEED_DEAD : NEED_MAIN;
        for (int i = threadIdx.x; i < NBIN; i += 256) h[i] = gh[i];
        __syncthreads();
        if (threadIdx.x < 64) {
            uint32_t s = 0;
#pragma unroll
            for (int j = 0; j < 32; j++) s += h[threadIdx.x * 32 + j];
            csum[threadIdx.x] = s;
        }
        __syncthreads();
        if (threadIdx.x == 0) {
            uint32_t cum = 0; int c = 63;
            for (; c > 0; c--) { uint32_t cc = csum[c]; if (cum + cc >= need) break; cum += cc; }
            int b = c * 32 + 31;
            for (; b > c * 32; b--) { uint32_t cc = h[b]; if (cum + cc >= need) break; cum += cc; }
            uint32_t extra = 0;
            for (int j = b + 1; j < b + REG_W && j < NBIN; j++) extra += h[j];
            scal[sel ? 2 : 0] = (uint32_t)b;
            scal[sel ? 3 : 1] = need - cum + extra;
        }
        __syncthreads();
    }
}

// ------- pull boundary-region (bins b*-REG_W .. b*+REG_W-1) from dense lists --------
__global__ __launch_bounds__(256) void bnd_filter_k(const uint2* __restrict__ cmpM,
                                                    const uint2* __restrict__ cmpD,
                                                    const uint32_t* __restrict__ scal,
                                                    uint2* __restrict__ bndM,
                                                    uint2* __restrict__ bndD,
                                                    uint32_t* __restrict__ cnts) {
    int sel = blockIdx.y;
    const uint2* list = sel ? cmpD : cmpM;
    uint2* bnd = sel ? bndD : bndM;
    uint32_t n = cnts[sel];
    uint32_t bs = scal[sel ? 2 : 0];
    for (uint32_t i = blockIdx.x * 256 + threadIdx.x; i < n; i += gridDim.x * 256) {
        uint2 ent = list[i];
        uint32_t bb = binOf(__uint_as_float(ent.y));
        if (bb + REG_W >= bs && bb <= bs + REG_W - 1) {
            uint32_t p = atomicAdd(&cnts[2 + sel], 1u);
            if (p < BNDCAP) bnd[p] = ent;
        }
    }
}

// ---------------- fp64 recompute, wave-per-candidate (4 per block) ----------------
__global__ __launch_bounds__(256) void bnd_f64_k(const uint2* __restrict__ bndM,
                                                 const uint2* __restrict__ bndD,
                                                 const uint32_t* __restrict__ cnts,
                                                 const float* __restrict__ x,
                                                 const float* __restrict__ w1,
                                                 const float* __restrict__ b1,
                                                 const float* __restrict__ b2,
                                                 double* __restrict__ bvM,
                                                 double* __restrict__ bvD) {
    int sel = blockIdx.y;
    const uint2* bnd = sel ? bndD : bndM;
    double* bv64 = sel ? bvD : bvM;
    uint32_t n = cnts[2 + sel]; if (n > BNDCAP) n = BNDCAP;
    uint32_t i = blockIdx.x * 4 + (threadIdx.x >> 6);
    if (i >= n) return;
    const int lane = threadIdx.x & 63;
    uint2 ent = bnd[i];
    uint32_t m = ent.x >> 14, s = ent.x & (S_ - 1);
    const float* xr = x + (size_t)m * H_;
    const float* wr = w1 + (size_t)s * H_;
    double sum = 0.0;
#pragma unroll
    for (int e = 0; e < 8; e++) {
        int k = lane + e * 64;
        sum += ((double)xr[k] - (double)b2[k]) * (double)wr[k];
    }
#pragma unroll
    for (int off = 32; off; off >>= 1) sum += __shfl_down(sum, off, 64);
    if (lane == 0) {
        double tot = sum + (double)b1[s];
        bv64[i] = tot > 0.0 ? tot : 0.0;
    }
}

// ------ exact top-r' in region: O(n) histogram-select + tie rank; DIRECT writes ------
__global__ __launch_bounds__(1024) void rank_hist_k(const uint2* __restrict__ bndM,
                                                    const double* __restrict__ bvM,
                                                    const uint2* __restrict__ bndD,
                                                    const double* __restrict__ bvD,
                                                    uint32_t* __restrict__ cnts,
                                                    const uint32_t* __restrict__ scal,
                                                    float* __restrict__ fsp,
                                                    uint2* __restrict__ entM,
                                                    uint2* __restrict__ entD,
                                                    uint32_t* __restrict__ rcM,
                                                    uint32_t* __restrict__ rcD) {
    int sel = blockIdx.x;
    const uint2* bnd = sel ? bndD : bndM;
    const double* bv = sel ? bvD : bvM;
    uint2* entries = sel ? entD : entM;
    uint32_t* rowCnt = sel ? rcD : rcM;
    const int capRow = sel ? CAPROW_D : CAPROW_M;
    uint32_t n = cnts[2 + sel]; if (n > BNDCAP) n = BNDCAP;
    uint32_t r = scal[sel ? 3 : 1]; if (r > n) r = n;
    uint32_t bs = scal[sel ? 2 : 0];
    uint32_t loBin = bs - (REG_W + PAD_BINS);
    uint32_t hiBin = bs + (REG_W + PAD_BINS);
    double lo = (double)__uint_as_float(BIN_BASE + (loBin << BIN_SHIFT));
    double hi = (double)__uint_as_float(BIN_BASE + (hiBin << BIN_SHIFT));
    double scale = (double)NSUB / (hi - lo);

    __shared__ uint32_t h[NSUB];
    __shared__ uint32_t cs[1024];
    __shared__ uint32_t c2[64];
    __shared__ uint32_t sCb, sAbove, sTieCnt;
    __shared__ double tieV[TIECAP];
    __shared__ uint2 tieE[TIECAP];
    const int t = threadIdx.x;
    for (int i = t; i < NSUB; i += 1024) h[i] = 0;
    if (t == 0) sTieCnt = 0;
    __syncthreads();
    for (uint32_t i = t; i < n; i += 1024) {
        double v = bv[i];
        int k = (int)((v - lo) * scale);
        k = k < 0 ? 0 : (k > NSUB - 1 ? NSUB - 1 : k);
        atomicAdd(&h[k], 1u);
    }
    __syncthreads();
    {
        uint32_t s = 0;
#pragma unroll
        for (int j = 0; j < 8; j++) s += h[t * 8 + j];
        cs[t] = s;
    }
    __syncthreads();
    if (t < 64) {
        uint32_t s = 0;
#pragma unroll
        for (int j = 0; j < 16; j++) s += cs[t * 16 + j];
        c2[t] = s;
    }
    __syncthreads();
    if (t == 0) {
        uint32_t cum = 0; int w2 = 63;
        for (; w2 > 0; w2--) { if (cum + c2[w2] >= r) break; cum += c2[w2]; }
        int c = w2 * 16 + 15;
        for (; c > w2 * 16; c--) { if (cum + cs[c] >= r) break; cum += cs[c]; }
        int b = c * 8 + 7;
        for (; b > c * 8; b--) { if (cum + h[b] >= r) break; cum += h[b]; }
        sCb = (uint32_t)b;
        sAbove = cum;
    }
    __syncthreads();
    const uint32_t cb = sCb;
    uint32_t rr = r - sAbove;
    const int lane = t & 63;
    const uint64_t lmlt = ((uint64_t)1 << lane) - 1;
    for (uint32_t i0 = 0; i0 < n; i0 += 1024) {
        uint32_t i = i0 + t;
        bool valid = i < n;
        double v = valid ? bv[i] : -1.0;
        uint32_t k = 0;
        if (valid) {
            int kk = (int)((v - lo) * scale);
            k = (uint32_t)(kk < 0 ? 0 : (kk > NSUB - 1 ? NSUB - 1 : kk));
        }
        if (valid && k > cb) {
            uint2 ent = bnd[i];
            float fv = __uint_as_float(ent.y);
            if (!sel) fsp[ent.x] = fv;
            uint32_t row = ent.x >> 14;
            uint32_t slot = atomicAdd(&rowCnt[row], 1u);
            if (slot < (uint32_t)capRow)
                entries[(size_t)row * capRow + slot] = make_uint2(ent.x & (S_ - 1), ent.y);
        }
        bool tie = valid && k == cb;
        uint64_t tm = __ballot(tie);
        if (tm) {
            uint32_t base = 0;
            if (lane == 0) base = atomicAdd(&sTieCnt, (uint32_t)__popcll(tm));
            base = __shfl(base, 0, 64);
            if (tie) {
                uint32_t p = base + __popcll(tm & lmlt);
                if (p < TIECAP) { tieV[p] = v; tieE[p] = bnd[i]; }
            }
        }
    }
    __syncthreads();
    uint32_t tc = sTieCnt; if (tc > TIECAP) tc = TIECAP;
    if (rr > tc) rr = tc;
    if (t < (int)tc) {
        double vi = tieV[t]; uint32_t ii = tieE[t].x;
        uint32_t rank = 0;
        for (uint32_t j = 0; j < tc; j++) {
            double vj = tieV[j]; uint32_t ij = tieE[j].x;
            rank += (vj > vi || (vj == vi && ij < ii)) ? 1u : 0u;
        }
        if (rank < rr) {
            uint2 ent = tieE[t];
            float fv = __uint_as_float(ent.y);
            if (!sel) fsp[ent.x] = fv;
            uint32_t row = ent.x >> 14;
            uint32_t slot = atomicAdd(&rowCnt[row], 1u);
            if (slot < (uint32_t)capRow)
                entries[(size_t)row * capRow + slot] = make_uint2(ent.x & (S_ - 1), ent.y);
        }
    }
}

// ---------------- scatter uncond picks (bins >= b*+REG_W) from dense lists ----------
__global__ __launch_bounds__(256) void scatter_list_k(const uint2* __restrict__ cmpM,
                                                      const uint2* __restrict__ cmpD,
                                                      const uint32_t* __restrict__ cnts,
                                                      const uint32_t* __restrict__ scal,
                                                      float* __restrict__ fsp,
                                                      uint2* __restrict__ entM,
                                                      uint2* __restrict__ entD,
                                                      uint32_t* __restrict__ rcM,
                                                      uint32_t* __restrict__ rcD) {
    int sel = blockIdx.y;
    const uint2* list = sel ? cmpD : cmpM;
    uint2* entries = sel ? entD : entM;
    uint32_t* rowCnt = sel ? rcD : rcM;
    int capRow = sel ? CAPROW_D : CAPROW_M;
    uint32_t n = cnts[sel];
    uint32_t bsReg = scal[sel ? 2 : 0] + REG_W - 1;
    for (uint32_t i = blockIdx.x * 256 + threadIdx.x; i < n; i += gridDim.x * 256) {
        uint2 ent = list[i];
        float v = __uint_as_float(ent.y);
        if (binOf(v) <= bsReg) continue;   // region handled by rank_hist_k
        if (!sel) fsp[ent.x] = v;
        uint32_t row = ent.x >> 14;
        uint32_t slot = atomicAdd(&rowCnt[row], 1u);
        if (slot < (uint32_t)capRow)
            entries[(size_t)row * capRow + slot] = make_uint2(ent.x & (S_ - 1), ent.y);
    }
}

// ---------------- sparse decode: x_rec & dead_x (bf16 W2T) ----------------
__global__ __launch_bounds__(512) void decode_k(const uint2* __restrict__ entM,
                                                const uint32_t* __restrict__ rcM,
                                                const uint2* __restrict__ entD,
                                                const uint32_t* __restrict__ rcD,
                                                const uint16_t* __restrict__ W2T,
                                                const float* __restrict__ b2,
                                                float* __restrict__ xrec,
                                                float* __restrict__ deadx) {
    __shared__ uint2 em[CAPROW_M];
    __shared__ uint2 ed[CAPROW_D];
    int b = blockIdx.x, h = threadIdx.x;
    uint32_t nm = rcM[b]; if (nm > CAPROW_M) nm = CAPROW_M;
    uint32_t nd = rcD[b]; if (nd > CAPROW_D) nd = CAPROW_D;
    for (uint32_t i = h; i < nm; i += 512) em[i] = entM[(size_t)b * CAPROW_M + i];
    for (uint32_t i = h; i < nd; i += 512) ed[i] = entD[(size_t)b * CAPROW_D + i];
    __syncthreads();
    float bias = b2[h];
    float a = bias, d = bias;
    for (uint32_t i = 0; i < nm; i++)
        a = fmaf(__uint_as_float(em[i].y), bf2f(W2T[(size_t)em[i].x * H_ + h]), a);
    for (uint32_t i = 0; i < nd; i++)
        d = fmaf(__uint_as_float(ed[i].y), bf2f(W2T[(size_t)ed[i].x * H_ + h]), d);
    xrec[(size_t)b * H_ + h] = a;
    deadx[(size_t)b * H_ + h] = d;
}

extern "C" void kernel_launch(void* const* d_in, const int* in_sizes, int n_in,
                              void* d_out, int out_size, void* d_ws, size_t ws_size,
                              hipStream_t stream) {
    const float* x = (const float*)d_in[0];
    const float* w1 = (const float*)d_in[1];
    const float* b1 = (const float*)d_in[2];
    const float* w2 = (const float*)d_in[3];
    const float* b2 = (const float*)d_in[4];
    const int* deadf = (const int*)d_in[5];

    float* out = (float*)d_out;
    float* xrec = out;
    float* fsp = out + (size_t)B_ * H_;
    float* deadx = out + (size_t)B_ * H_ + (size_t)B_ * S_;

    uint8_t* w = (uint8_t*)d_ws;
    size_t off = 0;
    auto alloc = [&](size_t bytes) { uint8_t* p = w + off; off = (off + bytes + 255) & ~(size_t)255; return p; };

    uint16_t* W2T = (uint16_t*)alloc((size_t)S_ * H_ * 2);
    uint8_t* ctrl = alloc(CTRL_BYTES);
    uint32_t* ghM = (uint32_t*)ctrl;
    uint32_t* ghD = (uint32_t*)(ctrl + NBIN * 4);
    uint32_t* cnts = (uint32_t*)(ctrl + NBIN * 8);         // [0]totM [1]totD [2]bndM [3]bndD
    uint32_t* scal = (uint32_t*)(ctrl + NBIN * 8 + 64);    // [0]bstarM [1]rM [2]bstarD [3]rD
    uint32_t* rcM = (uint32_t*)(ctrl + NBIN * 8 + 128);
    uint32_t* rcD = (uint32_t*)(ctrl + NBIN * 8 + 128 + B_ * 4);

    uint2* listM = (uint2*)alloc((size_t)NSEG * CAPSEG_M * 8);
    uint2* listD = (uint2*)alloc((size_t)NSEG * CAPSEG_D * 8);
    uint32_t* bcM = (uint32_t*)alloc((size_t)NSEG * 4);
    uint32_t* bcD = (uint32_t*)alloc((size_t)NSEG * 4);
    uint32_t* soM = (uint32_t*)alloc((size_t)NSEG * 4);
    uint32_t* soD = (uint32_t*)alloc((size_t)NSEG * 4);
    uint2* cmpM = (uint2*)alloc((size_t)NSEG * CAPSEG_M * 8);
    uint2* cmpD = (uint2*)alloc((size_t)NSEG * CAPSEG_D * 8);
    uint2* bndM = (uint2*)alloc((size_t)BNDCAP * 8);
    uint2* bndD = (uint2*)alloc((size_t)BNDCAP * 8);
    double* bvM = (double*)alloc((size_t)BNDCAP * 8);
    double* bvD = (double*)alloc((size_t)BNDCAP * 8);
    uint2* entM = (uint2*)alloc((size_t)B_ * CAPROW_M * 8);
    uint2* entD = (uint2*)alloc((size_t)B_ * CAPROW_D * 8);
    uint8_t* AhT = alloc((size_t)B_ * H_ * 2);
    uint8_t* WhT = alloc((size_t)S_ * H_ * 2);

    prep_k<<<13312 + ZBLK, 256, 0, stream>>>(w2, W2T, x, w1, b2, AhT, WhT, ctrl);
    gemm_fused<<<dim3(512, 8), 512, 0, stream>>>(AhT, WhT, b1, deadf,
                                                 listM, listD, bcM, bcD, fsp);
    seg_scan_k<<<1, 1024, 0, stream>>>(bcM, bcD, soM, soD, cnts);
    compact_hist_k<<<dim3(1024, 2), 256, 0, stream>>>(listM, listD, bcM, bcD, soM, soD,
                                                      cmpM, cmpD, ghM, ghD);
    scan_k<<<1, 256, 0, stream>>>(ghM, ghD, scal);
    bnd_filter_k<<<dim3(1024, 2), 256, 0, stream>>>(cmpM, cmpD, scal, bndM, bndD, cnts);
    bnd_f64_k<<<dim3(BNDCAP / 4, 2), 256, 0, stream>>>(bndM, bndD, cnts, x, w1, b1, b2, bvM, bvD);
    rank_hist_k<<<2, 1024, 0, stream>>>(bndM, bvM, bndD, bvD, cnts, scal,
                                        fsp, entM, entD, rcM, rcD);
    scatter_list_k<<<dim3(1024, 2), 256, 0, stream>>>(cmpM, cmpD, cnts, scal, fsp,
                                                      entM, entD, rcM, rcD);
    decode_k<<<B_, 512, 0, stream>>>(entM, rcM, entD, rcD, W2T, b2, xrec, deadx);
}

// Round 17
// 400.682 us; speedup vs baseline: 1.5844x; 1.0339x over previous
//
#include <hip/hip_runtime.h>
#include <stdint.h>

#define B_  4096
#define H_  512
#define S_  16384
#define KT_ 16            // H_/32 K-steps of 32
#define NEED_MAIN 131072  // K*B
#define NEED_DEAD 65536   // DEAD_K*B
#define DEAD_THRESH 5

#define T_LO 1.05078125f         // exact bin edge: 0x3F868000
#define BIN_BASE 0x3F800000u
#define BIN_SHIFT 13
#define NBIN 2048                // covers [1.0, 4.0)
#define REG_W 8                  // f64-rescue region = [b*-8, b*+7]; uncond >= b*+8
#define PAD_BINS 8               // 1-term gemm: f64 drift up to ~5 bins
#define NSUB 8192
#define TIECAP 512

#define NSEG 32768               // 4096 blocks x 8 waves
#define CAPSEG_M 128             // lambda ~21
#define CAPSEG_D 64              // lambda ~10
#define BNDCAP 16384
#define CAPROW_M 192
#define CAPROW_D 128

#define CTRL_BYTES (NBIN * 8 + 128 + B_ * 8)
#define CTRL_U4 ((CTRL_BYTES + 15) / 16)
#define ZBLK ((CTRL_U4 + 255) / 256)     // 13 blocks zero the ctrl region

typedef __bf16 bf16x8 __attribute__((ext_vector_type(8)));
typedef float f32x4 __attribute__((ext_vector_type(4)));
typedef unsigned short ushort8 __attribute__((ext_vector_type(8)));
typedef unsigned int uint4v __attribute__((ext_vector_type(4)));

__device__ __forceinline__ uint32_t binOf(float v) {
    uint32_t b = (__float_as_uint(v) - BIN_BASE) >> BIN_SHIFT;
    return b > (NBIN - 1) ? (NBIN - 1) : b;
}
__device__ __forceinline__ uint16_t f2bf(float f) {
    uint32_t u = __float_as_uint(f);
    uint32_t r = u + 0x7FFFu + ((u >> 16) & 1u);   // RNE
    return (uint16_t)(r >> 16);
}
__device__ __forceinline__ float bf2f(uint16_t b) {
    return __uint_as_float((uint32_t)b << 16);
}
__device__ __forceinline__ void gload16(const void* g, void* l) {
    __builtin_amdgcn_global_load_lds((const __attribute__((address_space(1))) uint32_t*)g,
                                     (__attribute__((address_space(3))) uint32_t*)l, 16, 0, 0);
}

// ------ fused prep: blocks 0..8191 transpose W2->bf16 W2T; 8192..13311 split x/w1;
//        blocks 13312.. zero the ctrl region (replaces hipMemsetAsync) -------------
__global__ __launch_bounds__(256) void prep_k(const float* __restrict__ W2,
                                              uint16_t* __restrict__ W2T,
                                              const float* __restrict__ x,
                                              const float* __restrict__ w1,
                                              const float* __restrict__ b2,
                                              uint8_t* __restrict__ AhT,
                                              uint8_t* __restrict__ WhT,
                                              uint8_t* __restrict__ ctrl) {
    __shared__ float tile[32][33];
    int b = blockIdx.x;
    if (b >= 13312) {
        uint32_t i = (uint32_t)(b - 13312) * 256 + threadIdx.x;
        if (i < CTRL_U4) {
            uint4v z = {0u, 0u, 0u, 0u};
            *(uint4v*)(ctrl + (size_t)i * 16) = z;
        }
        return;
    }
    if (b < 8192) {
        int s0 = (b & 511) * 32, h0 = (b >> 9) * 32;
        int tx = threadIdx.x & 31, ty = threadIdx.x >> 5;
#pragma unroll
        for (int i = 0; i < 4; i++) {
            int h = h0 + ty + i * 8;
            tile[ty + i * 8][tx] = W2[(size_t)h * S_ + s0 + tx];
        }
        __syncthreads();
#pragma unroll
        for (int i = 0; i < 4; i++) {
            int s = s0 + ty + i * 8;
            W2T[(size_t)s * H_ + h0 + tx] = f2bf(tile[tx][ty + i * 8]);
        }
        return;
    }
    int bb = b - 8192;
    int isX = bb < 1024;
    int tid = (isX ? bb : bb - 1024) * 256 + threadIdx.x;
    int r = tid >> 6, h8 = tid & 63;
    int k0 = h8 << 3;
    const float* src = isX ? x : w1;
    const float* s = src + (size_t)r * H_ + k0;
    float4 v0 = *(const float4*)s, v1 = *(const float4*)(s + 4);
    float a[8] = {v0.x, v0.y, v0.z, v0.w, v1.x, v1.y, v1.z, v1.w};
    if (isX) {
        float4 c0 = *(const float4*)(b2 + k0), c1 = *(const float4*)(b2 + k0 + 4);
        a[0] -= c0.x; a[1] -= c0.y; a[2] -= c0.z; a[3] -= c0.w;
        a[4] -= c1.x; a[5] -= c1.y; a[6] -= c1.z; a[7] -= c1.w;
    }
    ushort8 Hh;
#pragma unroll
    for (int e = 0; e < 8; e++) Hh[e] = f2bf(a[e]);
    int rb = r >> 7, kt = k0 >> 5;
    int mf = (r >> 4) & 7;
    int ln = (r & 15) | (((k0 >> 3) & 3) << 4);
    size_t byte = ((size_t)rb * KT_ + kt) * 8192 + (size_t)mf * 1024 + (size_t)ln * 16;
    if (isX) *(ushort8*)(AhT + byte) = Hh;
    else     *(ushort8*)(WhT + byte) = Hh;
}

// ------- f = relu((x-b2)@W1^T + b1) via 1x bf16 MFMA, 8 waves of 64x32, collect ------
__global__ __launch_bounds__(512, 8) void gemm_fused(const uint8_t* __restrict__ AhT,
                                                     const uint8_t* __restrict__ WhT,
                                                     const float* __restrict__ b1,
                                                     const int* __restrict__ deadf,
                                                     uint2* __restrict__ glM,
                                                     uint2* __restrict__ glD,
                                                     uint32_t* __restrict__ bcM,
                                                     uint32_t* __restrict__ bcD,
                                                     float* __restrict__ fsp) {
    __shared__ uint8_t lds[2][2][8192];   // [buf][Ah,Wh][tile]
    const int tid = threadIdx.x;
    const int lane = tid & 63, w = tid >> 6;     // 8 waves
    const int wr = w >> 2, wc = w & 3;           // wave tile 64x32
    const int lin = blockIdx.y * 512 + blockIdx.x;
    const int xcd = lin & 7, idx = lin >> 3;
    const int mb = xcd * 4 + (idx & 3), nb = idx >> 2;   // mb-fastest within XCD

    const uint8_t* gAh = AhT + (size_t)mb * KT_ * 8192;
    const uint8_t* gBh = WhT + (size_t)nb * KT_ * 8192;

    f32x4 acc[4][2];
#pragma unroll
    for (int i = 0; i < 4; i++)
#pragma unroll
        for (int j = 0; j < 2; j++) acc[i][j] = (f32x4){0.f, 0.f, 0.f, 0.f};

    auto stage = [&](int buf, int kt) {
        size_t tb = (size_t)kt * 8192;
        int o = tid * 16;
        gload16(gAh + tb + o, &lds[buf][0][o]);
        gload16(gBh + tb + o, &lds[buf][1][o]);
    };

    float* Fb = fsp + (size_t)(mb * 128) * S_ + nb * 128;
    const int zc4 = (tid & 31) * 4, zr0 = tid >> 5;
    const f32x4 zf4 = {0.f, 0.f, 0.f, 0.f};

    stage(0, 0);
    __syncthreads();
    for (int kt = 0; kt < KT_; kt++) {
        int cur = kt & 1;
        if (kt + 1 < KT_) stage(cur ^ 1, kt + 1);
        if (kt < 8)
            __builtin_nontemporal_store(zf4, (f32x4*)(Fb + (size_t)(zr0 + kt * 16) * S_ + zc4));
        bf16x8 ah[4], bh[2];
#pragma unroll
        for (int i = 0; i < 4; i++) {
            int offA = (wr * 4 + i) * 1024 + lane * 16;
            ah[i] = *(const bf16x8*)&lds[cur][0][offA];
        }
#pragma unroll
        for (int j = 0; j < 2; j++) {
            int offB = (wc * 2 + j) * 1024 + lane * 16;
            bh[j] = *(const bf16x8*)&lds[cur][1][offB];
        }
#pragma unroll
        for (int i = 0; i < 4; i++)
#pragma unroll
            for (int j = 0; j < 2; j++)
                acc[i][j] = __builtin_amdgcn_mfma_f32_16x16x32_bf16(ah[i], bh[j], acc[i][j], 0, 0, 0);
        __syncthreads();
    }

    const int col0 = nb * 128 + wc * 32 + (lane & 15);
    const int row0 = mb * 128 + wr * 64 + (lane >> 4) * 4;
    float b1v[2];
    int dd[2];
#pragma unroll
    for (int j = 0; j < 2; j++) {
        b1v[j] = b1[col0 + j * 16];
        dd[j] = (deadf[col0 + j * 16] >= DEAD_THRESH) ? 1 : 0;
    }
    const uint32_t gseg = (uint32_t)(mb * 128 + nb) * 8 + w;
    uint2* segM = glM + (size_t)gseg * CAPSEG_M;
    uint2* segD = glD + (size_t)gseg * CAPSEG_D;
    const uint64_t lmlt = ((uint64_t)1 << lane) - 1;
    uint32_t runM = 0, runD = 0;
#pragma unroll
    for (int i = 0; i < 4; i++)
#pragma unroll
        for (int j = 0; j < 2; j++)
#pragma unroll
            for (int r = 0; r < 4; r++) {
                float v = fmaxf(acc[i][j][r] + b1v[j], 0.0f);
                bool pass = v >= T_LO;
                uint64_t mask = __ballot(pass);
                if (mask) {
                    uint32_t prefix = (uint32_t)__popcll(mask & lmlt);
                    uint2 ent;
                    ent.x = (uint32_t)(row0 + i * 16 + r) * S_ + (uint32_t)(col0 + j * 16);
                    ent.y = __float_as_uint(v);
                    if (pass && runM + prefix < CAPSEG_M) segM[runM + prefix] = ent;
                    runM += (uint32_t)__popcll(mask);
                    bool dp = pass && dd[j];
                    uint64_t dmask = __ballot(dp);
                    if (dmask) {
                        uint32_t dprefix = (uint32_t)__popcll(dmask & lmlt);
                        if (dp && runD + dprefix < CAPSEG_D) segD[runD + dprefix] = ent;
                        runD += (uint32_t)__popcll(dmask);
                    }
                }
            }
    if (lane == 0) {
        bcM[gseg] = runM < CAPSEG_M ? runM : CAPSEG_M;
        bcD[gseg] = runD < CAPSEG_D ? runD : CAPSEG_D;
    }
}

// -------- parallel exclusive prefix over 32768 segment counts (1024 thr, uint4) ------
__global__ __launch_bounds__(1024) void seg_scan_k(const uint32_t* __restrict__ bcM,
                                                   const uint32_t* __restrict__ bcD,
                                                   uint32_t* __restrict__ soM,
                                                   uint32_t* __restrict__ soD,
                                                   uint32_t* __restrict__ cnts) {
    __shared__ uint32_t part[1024];
    const int t = threadIdx.x;
    for (int sel = 0; sel < 2; sel++) {
        const uint32_t* bc = sel ? bcD : bcM;
        uint32_t* so = sel ? soD : soM;
        const uint4* b4 = (const uint4*)(bc + t * 32);
        uint32_t s = 0;
#pragma unroll
        for (int i = 0; i < 8; i++) {
            uint4 v = b4[i];
            s += v.x + v.y + v.z + v.w;
        }
        part[t] = s;
        __syncthreads();
        for (int d = 1; d < 1024; d <<= 1) {
            uint32_t v = (t >= d) ? part[t - d] : 0;
            __syncthreads();
            part[t] += v;
            __syncthreads();
        }
        uint32_t run = (t == 0) ? 0 : part[t - 1];
        uint4* so4 = (uint4*)(so + t * 32);
#pragma unroll
        for (int i = 0; i < 8; i++) {
            uint4 v = b4[i];
            uint4 o;
            o.x = run; run += v.x;
            o.y = run; run += v.y;
            o.z = run; run += v.z;
            o.w = run; run += v.w;
            so4[i] = o;
        }
        if (t == 1023) cnts[sel] = run;
        __syncthreads();
    }
}

// ---------------- compact segments to dense lists + histogram, y=0 M / y=1 D ------
__global__ __launch_bounds__(256) void compact_hist_k(const uint2* __restrict__ glM,
                                                      const uint2* __restrict__ glD,
                                                      const uint32_t* __restrict__ bcM,
                                                      const uint32_t* __restrict__ bcD,
                                                      const uint32_t* __restrict__ soM,
                                                      const uint32_t* __restrict__ soD,
                                                      uint2* __restrict__ cmpM,
                                                      uint2* __restrict__ cmpD,
                                                      uint32_t* __restrict__ ghM,
                                                      uint32_t* __restrict__ ghD) {
    __shared__ uint32_t h[NBIN];
    int sel = blockIdx.y;
    const uint2* list = sel ? glD : glM;
    const uint32_t* bc = sel ? bcD : bcM;
    const uint32_t* so = sel ? soD : soM;
    uint2* cmp = sel ? cmpD : cmpM;
    uint32_t cap = sel ? CAPSEG_D : CAPSEG_M;
    uint32_t* gh = sel ? ghD : ghM;
    for (int i = threadIdx.x; i < NBIN; i += 256) h[i] = 0;
    __syncthreads();
    const int wv = threadIdx.x >> 6, lane = threadIdx.x & 63;
    for (uint32_t seg = blockIdx.x * 4 + wv; seg < NSEG; seg += gridDim.x * 4) {
        uint32_t n = bc[seg], off = so[seg];
        for (uint32_t i = lane; i < n; i += 64) {
            uint2 e = list[(size_t)seg * cap + i];
            cmp[off + i] = e;
            atomicAdd(&h[binOf(__uint_as_float(e.y))], 1u);
        }
    }
    __syncthreads();
    for (int i = threadIdx.x; i < NBIN; i += 256)
        if (h[i]) atomicAdd(&gh[i], h[i]);
}

// ---------------- find boundary bin b* (parallel chunked scan) ----------------
__global__ __launch_bounds__(256) void scan_k(const uint32_t* __restrict__ ghM,
                                              const uint32_t* __restrict__ ghD,
                                              uint32_t* __restrict__ scal) {
    __shared__ uint32_t h[NBIN];
    __shared__ uint32_t csum[64];
    for (int sel = 0; sel < 2; sel++) {
        const uint32_t* gh = sel ? ghD : ghM;
        uint32_t need = sel ? NEED_DEAD : NEED_MAIN;
        for (int i = threadIdx.x; i < NBIN; i += 256) h[i] = gh[i];
        __syncthreads();
        if (threadIdx.x < 64) {
            uint32_t s = 0;
#pragma unroll
            for (int j = 0; j < 32; j++) s += h[threadIdx.x * 32 + j];
            csum[threadIdx.x] = s;
        }
        __syncthreads();
        if (threadIdx.x == 0) {
            uint32_t cum = 0; int c = 63;
            for (; c > 0; c--) { uint32_t cc = csum[c]; if (cum + cc >= need) break; cum += cc; }
            int b = c * 32 + 31;
            for (; b > c * 32; b--) { uint32_t cc = h[b]; if (cum + cc >= need) break; cum += cc; }
            uint32_t extra = 0;
            for (int j = b + 1; j < b + REG_W && j < NBIN; j++) extra += h[j];
            scal[sel ? 2 : 0] = (uint32_t)b;
            scal[sel ? 3 : 1] = need - cum + extra;
        }
        __syncthreads();
    }
}

// ---- merged: region entries -> bnd; above-region entries -> fsp/ent scatter --------
__global__ __launch_bounds__(256) void filter_scatter_k(const uint2* __restrict__ cmpM,
                                                        const uint2* __restrict__ cmpD,
                                                        const uint32_t* __restrict__ scal,
                                                        uint2* __restrict__ bndM,
                                                        uint2* __restrict__ bndD,
                                                        uint32_t* __restrict__ cnts,
                                                        float* __restrict__ fsp,
                                                        uint2* __restrict__ entM,
                                                        uint2* __restrict__ entD,
                                                        uint32_t* __restrict__ rcM,
                                                        uint32_t* __restrict__ rcD) {
    int sel = blockIdx.y;
    const uint2* list = sel ? cmpD : cmpM;
    uint2* bnd = sel ? bndD : bndM;
    uint2* entries = sel ? entD : entM;
    uint32_t* rowCnt = sel ? rcD : rcM;
    int capRow = sel ? CAPROW_D : CAPROW_M;
    uint32_t n = cnts[sel];
    uint32_t bs = scal[sel ? 2 : 0];
    for (uint32_t i = blockIdx.x * 256 + threadIdx.x; i < n; i += gridDim.x * 256) {
        uint2 ent = list[i];
        float v = __uint_as_float(ent.y);
        uint32_t bb = binOf(v);
        if (bb + REG_W < bs) continue;          // below region: dropped
        if (bb <= bs + REG_W - 1) {             // region: to f64 rescue
            uint32_t p = atomicAdd(&cnts[2 + sel], 1u);
            if (p < BNDCAP) bnd[p] = ent;
            continue;
        }
        // unconditional keep
        if (!sel) fsp[ent.x] = v;
        uint32_t row = ent.x >> 14;
        uint32_t slot = atomicAdd(&rowCnt[row], 1u);
        if (slot < (uint32_t)capRow)
            entries[(size_t)row * capRow + slot] = make_uint2(ent.x & (S_ - 1), ent.y);
    }
}

// ---------------- fp64 recompute, wave-per-candidate (4 per block) ----------------
__global__ __launch_bounds__(256) void bnd_f64_k(const uint2* __restrict__ bndM,
                                                 const uint2* __restrict__ bndD,
                                                 const uint32_t* __restrict__ cnts,
                                                 const float* __restrict__ x,
                                                 const float* __restrict__ w1,
                                                 const float* __restrict__ b1,
                                                 const float* __restrict__ b2,
                                                 double* __restrict__ bvM,
                                                 double* __restrict__ bvD) {
    int sel = blockIdx.y;
    const uint2* bnd = sel ? bndD : bndM;
    double* bv64 = sel ? bvD : bvM;
    uint32_t n = cnts[2 + sel]; if (n > BNDCAP) n = BNDCAP;
    uint32_t i = blockIdx.x * 4 + (threadIdx.x >> 6);
    if (i >= n) return;
    const int lane = threadIdx.x & 63;
    uint2 ent = bnd[i];
    uint32_t m = ent.x >> 14, s = ent.x & (S_ - 1);
    const float* xr = x + (size_t)m * H_;
    const float* wr = w1 + (size_t)s * H_;
    double sum = 0.0;
#pragma unroll
    for (int e = 0; e < 8; e++) {
        int k = lane + e * 64;
        sum += ((double)xr[k] - (double)b2[k]) * (double)wr[k];
    }
#pragma unroll
    for (int off = 32; off; off >>= 1) sum += __shfl_down(sum, off, 64);
    if (lane == 0) {
        double tot = sum + (double)b1[s];
        bv64[i] = tot > 0.0 ? tot : 0.0;
    }
}

// ------ exact top-r' in region: O(n) histogram-select + tie rank; DIRECT writes ------
__global__ __launch_bounds__(1024) void rank_hist_k(const uint2* __restrict__ bndM,
                                                    const double* __restrict__ bvM,
                                                    const uint2* __restrict__ bndD,
                                                    const double* __restrict__ bvD,
                                                    uint32_t* __restrict__ cnts,
                                                    const uint32_t* __restrict__ scal,
                                                    float* __restrict__ fsp,
                                                    uint2* __restrict__ entM,
                                                    uint2* __restrict__ entD,
                                                    uint32_t* __restrict__ rcM,
                                                    uint32_t* __restrict__ rcD) {
    int sel = blockIdx.x;
    const uint2* bnd = sel ? bndD : bndM;
    const double* bv = sel ? bvD : bvM;
    uint2* entries = sel ? entD : entM;
    uint32_t* rowCnt = sel ? rcD : rcM;
    const int capRow = sel ? CAPROW_D : CAPROW_M;
    uint32_t n = cnts[2 + sel]; if (n > BNDCAP) n = BNDCAP;
    uint32_t r = scal[sel ? 3 : 1]; if (r > n) r = n;
    uint32_t bs = scal[sel ? 2 : 0];
    uint32_t loBin = bs - (REG_W + PAD_BINS);
    uint32_t hiBin = bs + (REG_W + PAD_BINS);
    double lo = (double)__uint_as_float(BIN_BASE + (loBin << BIN_SHIFT));
    double hi = (double)__uint_as_float(BIN_BASE + (hiBin << BIN_SHIFT));
    double scale = (double)NSUB / (hi - lo);

    __shared__ uint32_t h[NSUB];
    __shared__ uint32_t cs[1024];
    __shared__ uint32_t c2[64];
    __shared__ uint32_t sCb, sAbove, sTieCnt;
    __shared__ double tieV[TIECAP];
    __shared__ uint2 tieE[TIECAP];
    const int t = threadIdx.x;
    for (int i = t; i < NSUB; i += 1024) h[i] = 0;
    if (t == 0) sTieCnt = 0;
    __syncthreads();
    for (uint32_t i = t; i < n; i += 1024) {
        double v = bv[i];
        int k = (int)((v - lo) * scale);
        k = k < 0 ? 0 : (k > NSUB - 1 ? NSUB - 1 : k);
        atomicAdd(&h[k], 1u);
    }
    __syncthreads();
    {
        uint32_t s = 0;
#pragma unroll
        for (int j = 0; j < 8; j++) s += h[t * 8 + j];
        cs[t] = s;
    }
    __syncthreads();
    if (t < 64) {
        uint32_t s = 0;
#pragma unroll
        for (int j = 0; j < 16; j++) s += cs[t * 16 + j];
        c2[t] = s;
    }
    __syncthreads();
    if (t == 0) {
        uint32_t cum = 0; int w2 = 63;
        for (; w2 > 0; w2--) { if (cum + c2[w2] >= r) break; cum += c2[w2]; }
        int c = w2 * 16 + 15;
        for (; c > w2 * 16; c--) { if (cum + cs[c] >= r) break; cum += cs[c]; }
        int b = c * 8 + 7;
        for (; b > c * 8; b--) { if (cum + h[b] >= r) break; cum += h[b]; }
        sCb = (uint32_t)b;
        sAbove = cum;
    }
    __syncthreads();
    const uint32_t cb = sCb;
    uint32_t rr = r - sAbove;
    const int lane = t & 63;
    const uint64_t lmlt = ((uint64_t)1 << lane) - 1;
    for (uint32_t i0 = 0; i0 < n; i0 += 1024) {
        uint32_t i = i0 + t;
        bool valid = i < n;
        double v = valid ? bv[i] : -1.0;
        uint32_t k = 0;
        if (valid) {
            int kk = (int)((v - lo) * scale);
            k = (uint32_t)(kk < 0 ? 0 : (kk > NSUB - 1 ? NSUB - 1 : kk));
        }
        if (valid && k > cb) {
            uint2 ent = bnd[i];
            float fv = __uint_as_float(ent.y);
            if (!sel) fsp[ent.x] = fv;
            uint32_t row = ent.x >> 14;
            uint32_t slot = atomicAdd(&rowCnt[row], 1u);
            if (slot < (uint32_t)capRow)
                entries[(size_t)row * capRow + slot] = make_uint2(ent.x & (S_ - 1), ent.y);
        }
        bool tie = valid && k == cb;
        uint64_t tm = __ballot(tie);
        if (tm) {
            uint32_t base = 0;
            if (lane == 0) base = atomicAdd(&sTieCnt, (uint32_t)__popcll(tm));
            base = __shfl(base, 0, 64);
            if (tie) {
                uint32_t p = base + __popcll(tm & lmlt);
                if (p < TIECAP) { tieV[p] = v; tieE[p] = bnd[i]; }
            }
        }
    }
    __syncthreads();
    uint32_t tc = sTieCnt; if (tc > TIECAP) tc = TIECAP;
    if (rr > tc) rr = tc;
    if (t < (int)tc) {
        double vi = tieV[t]; uint32_t ii = tieE[t].x;
        uint32_t rank = 0;
        for (uint32_t j = 0; j < tc; j++) {
            double vj = tieV[j]; uint32_t ij = tieE[j].x;
            rank += (vj > vi || (vj == vi && ij < ii)) ? 1u : 0u;
        }
        if (rank < rr) {
            uint2 ent = tieE[t];
            float fv = __uint_as_float(ent.y);
            if (!sel) fsp[ent.x] = fv;
            uint32_t row = ent.x >> 14;
            uint32_t slot = atomicAdd(&rowCnt[row], 1u);
            if (slot < (uint32_t)capRow)
                entries[(size_t)row * capRow + slot] = make_uint2(ent.x & (S_ - 1), ent.y);
        }
    }
}

// ---------------- sparse decode: x_rec & dead_x (bf16 W2T) ----------------
__global__ __launch_bounds__(512) void decode_k(const uint2* __restrict__ entM,
                                                const uint32_t* __restrict__ rcM,
                                                const uint2* __restrict__ entD,
                                                const uint32_t* __restrict__ rcD,
                                                const uint16_t* __restrict__ W2T,
                                                const float* __restrict__ b2,
                                                float* __restrict__ xrec,
                                                float* __restrict__ deadx) {
    __shared__ uint2 em[CAPROW_M];
    __shared__ uint2 ed[CAPROW_D];
    int b = blockIdx.x, h = threadIdx.x;
    uint32_t nm = rcM[b]; if (nm > CAPROW_M) nm = CAPROW_M;
    uint32_t nd = rcD[b]; if (nd > CAPROW_D) nd = CAPROW_D;
    for (uint32_t i = h; i < nm; i += 512) em[i] = entM[(size_t)b * CAPROW_M + i];
    for (uint32_t i = h; i < nd; i += 512) ed[i] = entD[(size_t)b * CAPROW_D + i];
    __syncthreads();
    float bias = b2[h];
    float a = bias, d = bias;
    for (uint32_t i = 0; i < nm; i++)
        a = fmaf(__uint_as_float(em[i].y), bf2f(W2T[(size_t)em[i].x * H_ + h]), a);
    for (uint32_t i = 0; i < nd; i++)
        d = fmaf(__uint_as_float(ed[i].y), bf2f(W2T[(size_t)ed[i].x * H_ + h]), d);
    xrec[(size_t)b * H_ + h] = a;
    deadx[(size_t)b * H_ + h] = d;
}

extern "C" void kernel_launch(void* const* d_in, const int* in_sizes, int n_in,
                              void* d_out, int out_size, void* d_ws, size_t ws_size,
                              hipStream_t stream) {
    const float* x = (const float*)d_in[0];
    const float* w1 = (const float*)d_in[1];
    const float* b1 = (const float*)d_in[2];
    const float* w2 = (const float*)d_in[3];
    const float* b2 = (const float*)d_in[4];
    const int* deadf = (const int*)d_in[5];

    float* out = (float*)d_out;
    float* xrec = out;
    float* fsp = out + (size_t)B_ * H_;
    float* deadx = out + (size_t)B_ * H_ + (size_t)B_ * S_;

    uint8_t* w = (uint8_t*)d_ws;
    size_t off = 0;
    auto alloc = [&](size_t bytes) { uint8_t* p = w + off; off = (off + bytes + 255) & ~(size_t)255; return p; };

    uint16_t* W2T = (uint16_t*)alloc((size_t)S_ * H_ * 2);
    uint8_t* ctrl = alloc(CTRL_BYTES);
    uint32_t* ghM = (uint32_t*)ctrl;
    uint32_t* ghD = (uint32_t*)(ctrl + NBIN * 4);
    uint32_t* cnts = (uint32_t*)(ctrl + NBIN * 8);         // [0]totM [1]totD [2]bndM [3]bndD
    uint32_t* scal = (uint32_t*)(ctrl + NBIN * 8 + 64);    // [0]bstarM [1]rM [2]bstarD [3]rD
    uint32_t* rcM = (uint32_t*)(ctrl + NBIN * 8 + 128);
    uint32_t* rcD = (uint32_t*)(ctrl + NBIN * 8 + 128 + B_ * 4);

    uint2* listM = (uint2*)alloc((size_t)NSEG * CAPSEG_M * 8);
    uint2* listD = (uint2*)alloc((size_t)NSEG * CAPSEG_D * 8);
    uint32_t* bcM = (uint32_t*)alloc((size_t)NSEG * 4);
    uint32_t* bcD = (uint32_t*)alloc((size_t)NSEG * 4);
    uint32_t* soM = (uint32_t*)alloc((size_t)NSEG * 4);
    uint32_t* soD = (uint32_t*)alloc((size_t)NSEG * 4);
    uint2* cmpM = (uint2*)alloc((size_t)NSEG * CAPSEG_M * 8);
    uint2* cmpD = (uint2*)alloc((size_t)NSEG * CAPSEG_D * 8);
    uint2* bndM = (uint2*)alloc((size_t)BNDCAP * 8);
    uint2* bndD = (uint2*)alloc((size_t)BNDCAP * 8);
    double* bvM = (double*)alloc((size_t)BNDCAP * 8);
    double* bvD = (double*)alloc((size_t)BNDCAP * 8);
    uint2* entM = (uint2*)alloc((size_t)B_ * CAPROW_M * 8);
    uint2* entD = (uint2*)alloc((size_t)B_ * CAPROW_D * 8);
    uint8_t* AhT = alloc((size_t)B_ * H_ * 2);
    uint8_t* WhT = alloc((size_t)S_ * H_ * 2);

    prep_k<<<13312 + ZBLK, 256, 0, stream>>>(w2, W2T, x, w1, b2, AhT, WhT, ctrl);
    gemm_fused<<<dim3(512, 8), 512, 0, stream>>>(AhT, WhT, b1, deadf,
                                                 listM, listD, bcM, bcD, fsp);
    seg_scan_k<<<1, 1024, 0, stream>>>(bcM, bcD, soM, soD, cnts);
    compact_hist_k<<<dim3(1024, 2), 256, 0, stream>>>(listM, listD, bcM, bcD, soM, soD,
                                                      cmpM, cmpD, ghM, ghD);
    scan_k<<<1, 256, 0, stream>>>(ghM, ghD, scal);
    filter_scatter_k<<<dim3(1024, 2), 256, 0, stream>>>(cmpM, cmpD, scal, bndM, bndD, cnts,
                                                        fsp, entM, entD, rcM, rcD);
    bnd_f64_k<<<dim3(BNDCAP / 4, 2), 256, 0, stream>>>(bndM, bndD, cnts, x, w1, b1, b2, bvM, bvD);
    rank_hist_k<<<2, 1024, 0, stream>>>(bndM, bvM, bndD, bvD, cnts, scal,
                                        fsp, entM, entD, rcM, rcD);
    decode_k<<<B_, 512, 0, stream>>>(entM, rcM, entD, rcD, W2T, b2, xrec, deadx);
}